// Round 1
// baseline (429.543 us; speedup 1.0000x reference)
//
#include <hip/hip_runtime.h>
#include <hip/hip_bf16.h>
#include <cstdint>
#include <cstddef>

namespace {

constexpr int kB = 512, kT = 32, kH = 768, kF = 3072, kE = 3;
constexpr int kMaxTiles = 131;   // sum ceil(cnt_e/4) <= 131
constexpr int kMaxChunk = 131;
constexpr int kXPermTile = 128 * kH;   // 98304 elts per tile
constexpr int kHbufTile  = 128 * kF;   // 393216 elts per tile

typedef __attribute__((ext_vector_type(8))) short short8;
typedef __attribute__((ext_vector_type(4))) float f32x4;

__device__ __forceinline__ void gld_lds16(const void* g, void* l) {
  __builtin_amdgcn_global_load_lds(
      (const __attribute__((address_space(1))) void*)g,
      (__attribute__((address_space(3))) void*)l, 16, 0, 0);
}

__device__ __forceinline__ float bf2f(__hip_bfloat16 v) { return __bfloat162float(v); }
__device__ __forceinline__ float bfu(unsigned short u) {
  return __uint_as_float(((unsigned)u) << 16);
}
__device__ __forceinline__ unsigned short f2bfb(float f) {
  __hip_bfloat16 h = __float2bfloat16(f);
  return *reinterpret_cast<unsigned short*>(&h);
}

// exact-grade gelu: Abramowitz-Stegun 7.1.26 erf, |err| <= 1.5e-7 (vs ~40-op ocml erff)
__device__ __forceinline__ float gelu_f(float v) {
  float av = fabsf(v);
  float z = av * 0.70710678118654752f;
  float t = __builtin_amdgcn_rcpf(fmaf(0.3275911f, z, 1.0f));
  float p = fmaf(fmaf(fmaf(fmaf(1.061405429f, t, -1.453152027f), t, 1.421413741f),
                      t, -0.284496736f), t, 0.254829592f) * t;
  float er = fmaf(-p, __expf(-z * z), 1.0f);   // erf(z), z >= 0
  return 0.5f * v + 0.5f * av * er;
}

// ---- fused per-tensor dtype sniff (4 blocks) + workspace re-init ----
__global__ void k_sniff_all(const unsigned short* __restrict__ x,
                            const unsigned short* __restrict__ g,
                            const unsigned short* __restrict__ w1,
                            const unsigned short* __restrict__ w2,
                            int* __restrict__ flags, int* __restrict__ cnt,
                            int* __restrict__ ticket) {
  int bb = blockIdx.x;
  if (bb == 0 && threadIdx.x < 4) {
    if (threadIdx.x < 3) cnt[threadIdx.x] = 0;
    else *ticket = 0;
  }
  const unsigned short* p = (bb == 0) ? x : (bb == 1) ? g : (bb == 2) ? w1 : w2;
  int nwords = (bb == 1) ? kE * kH : 4096;
  __shared__ int cnt_s;
  if (threadIdx.x == 0) cnt_s = 0;
  __syncthreads();
  int local = 0;
  for (int i = threadIdx.x; i < nwords; i += 256) {
    unsigned e = (p[i] >> 7) & 0xFF;
    if (e >= 0xC0) ++local;
  }
  atomicAdd(&cnt_s, local);
  __syncthreads();
  if (threadIdx.x == 0) flags[bb] = (cnt_s > 64) ? 1 : 0;
}

// ---------------- routing (vectorized) + tile packing in last block ----------------
__global__ void k_route(const void* __restrict__ xv, const void* __restrict__ Wgv,
                        const int* __restrict__ flags,
                        float* __restrict__ wsel,
                        int* __restrict__ cnt, int* __restrict__ lists,
                        int* __restrict__ ticket,
                        int* __restrict__ tileExpert, int* __restrict__ tileBatch,
                        int* __restrict__ numTiles) {
  bool fx = (flags[0] != 0), fg = (flags[1] != 0);
  int b = blockIdx.x;
  int tid = threadIdx.x;
  float a0 = 0.f, a1 = 0.f, a2 = 0.f;
  if (tid < 192) {   // 192 * float4 = 768 h
    float m0 = 0.f, m1 = 0.f, m2 = 0.f, m3 = 0.f;
    if (fx) {
      const float4* xr = (const float4*)((const float*)xv + (size_t)b * kT * kH) + tid;
#pragma unroll 8
      for (int t = 0; t < kT; ++t) {
        float4 u = xr[t * 192];
        m0 += u.x; m1 += u.y; m2 += u.z; m3 += u.w;
      }
    } else {
      const ushort4* xr = (const ushort4*)((const unsigned short*)xv + (size_t)b * kT * kH) + tid;
#pragma unroll 8
      for (int t = 0; t < kT; ++t) {
        ushort4 u = xr[t * 192];
        m0 += bfu(u.x); m1 += bfu(u.y); m2 += bfu(u.z); m3 += bfu(u.w);
      }
    }
    const float inv = 1.f / kT;
    m0 *= inv; m1 *= inv; m2 *= inv; m3 *= inv;
#pragma unroll
    for (int e = 0; e < kE; ++e) {
      float w0, w1v, w2v, w3;
      int base = e * kH + tid * 4;
      if (fg) {
        float4 u = *(const float4*)((const float*)Wgv + base);
        w0 = u.x; w1v = u.y; w2v = u.z; w3 = u.w;
      } else {
        ushort4 u = *(const ushort4*)((const unsigned short*)Wgv + base);
        w0 = bfu(u.x); w1v = bfu(u.y); w2v = bfu(u.z); w3 = bfu(u.w);
      }
      float d = m0 * w0 + m1 * w1v + m2 * w2v + m3 * w3;
      if (e == 0) a0 = d; else if (e == 1) a1 = d; else a2 = d;
    }
  }
  __shared__ float red[3][256];
  red[0][tid] = a0; red[1][tid] = a1; red[2][tid] = a2;
  __syncthreads();
  for (int s2 = 128; s2 > 0; s2 >>= 1) {
    if (tid < s2) {
      red[0][tid] += red[0][tid + s2];
      red[1][tid] += red[1][tid + s2];
      red[2][tid] += red[2][tid + s2];
    }
    __syncthreads();
  }
  if (tid == 0) {
    float l0 = red[0][0], l1 = red[1][0], l2 = red[2][0];
    int am = 0; float mx = l0;
    if (l1 > mx) { mx = l1; am = 1; }
    if (l2 > mx) { mx = l2; am = 2; }
    float e0 = expf(l0 - mx), e1 = expf(l1 - mx), e2 = expf(l2 - mx);
    float inv = 1.f / (e0 + e1 + e2);
    float sc = (am == 0 ? e0 : (am == 1 ? e1 : e2)) * inv;
    wsel[b] = sc;
    int pos = atomicAdd(&cnt[am], 1);
    lists[am * kB + pos] = b;
    __threadfence();                       // publish lists/cnt (release)
    int tk = atomicAdd(ticket, 1);
    if (tk == kB - 1) {                    // last block packs the tiles
      __threadfence();                     // acquire side
      int t = 0;
      for (int e = 0; e < kE; ++e) {
        int c = cnt[e];
        for (int i = 0; i < c; i += 4) {
          tileExpert[t] = e;
          for (int s = 0; s < 4; ++s)
            tileBatch[t * 4 + s] = (i + s < c) ? lists[e * kB + i + s] : -1;
          ++t;
        }
      }
      *numTiles = t;
      for (int tt = t; tt < kMaxTiles; ++tt) {
        tileExpert[tt] = 0;
        for (int s = 0; s < 4; ++s) tileBatch[tt * 4 + s] = -1;
      }
    }
  }
}

// ---------------- fused transpose + convert: both weight tensors, one launch ----------------
// z<3: W1 [e][H][F] -> w1t [e][F][H]; z>=3: W2 [e][F][H] -> w2t [e][H][F]
__global__ __launch_bounds__(256)
void k_transpose6(const void* __restrict__ w1src, const void* __restrict__ w2src,
                  __hip_bfloat16* __restrict__ w1dst, __hip_bfloat16* __restrict__ w2dst,
                  const int* __restrict__ flags) {
  int z = blockIdx.z;
  bool isW1 = (z < 3);
  int e = isW1 ? z : z - 3;
  bool f32 = (flags[isW1 ? 2 : 3] != 0);
  const float* sf = (const float*)(isW1 ? w1src : w2src);
  const unsigned short* sb = (const unsigned short*)(isW1 ? w1src : w2src);
  unsigned short* dst = (unsigned short*)(isW1 ? w1dst : w2dst);
  int K = isW1 ? kH : kF, N = isW1 ? kF : kH;
  int ntx = N / 64;
  int bx = blockIdx.x;
  int n0 = (bx % ntx) * 64, k0 = (bx / ntx) * 64;
  __shared__ __align__(16) unsigned short t[64][73];
  size_t eoff = (size_t)e * K * N;
  int tr = threadIdx.x >> 4;
  int tc4 = (threadIdx.x & 15) * 4;
#pragma unroll
  for (int i = 0; i < 4; ++i) {
    int r = tr + 16 * i;
    size_t idx = eoff + (size_t)(k0 + r) * N + n0 + tc4;
    if (f32) {
      float4 u = *(const float4*)(sf + idx);
      t[r][tc4] = f2bfb(u.x); t[r][tc4 + 1] = f2bfb(u.y);
      t[r][tc4 + 2] = f2bfb(u.z); t[r][tc4 + 3] = f2bfb(u.w);
    } else {
      ushort4 u = *(const ushort4*)(sb + idx);
      t[r][tc4] = u.x; t[r][tc4 + 1] = u.y; t[r][tc4 + 2] = u.z; t[r][tc4 + 3] = u.w;
    }
  }
  __syncthreads();
#pragma unroll
  for (int i = 0; i < 4; ++i) {
    int rn = tr + 16 * i;
    ushort4 v;
    v.x = t[tc4][rn]; v.y = t[tc4 + 1][rn]; v.z = t[tc4 + 2][rn]; v.w = t[tc4 + 3][rn];
    *(ushort4*)(dst + eoff + (size_t)(n0 + rn) * K + k0 + tc4) = v;
  }
}

// ---------------- convert + permute x into ffn1 A-staging order ----------------
__global__ __launch_bounds__(256)
void k_convert_x(const void* __restrict__ xv, const int* __restrict__ flags,
                 const int* __restrict__ tileBatch, const int* __restrict__ numTiles,
                 __hip_bfloat16* __restrict__ xperm) {
  int tile = blockIdx.y;
  if (tile >= *numTiles) return;
  int kblk = blockIdx.x;
  bool fx = (flags[0] != 0);
  const float* xf = (const float*)xv;
  const __hip_bfloat16* xb = (const __hip_bfloat16*)xv;
  int tb0 = tileBatch[tile * 4];
  int tb[4];
#pragma unroll
  for (int s = 0; s < 4; ++s) {
    int bb = tileBatch[tile * 4 + s];
    tb[s] = (bb < 0) ? tb0 : bb;
  }
  int tid = threadIdx.x;
  short8* dst = (short8*)(xperm + (size_t)tile * kXPermTile + kblk * 8192);
#pragma unroll
  for (int i = 0; i < 4; ++i) {
    int s = i * 256 + tid;
    int m = (s >> 2) & 127, kk = s >> 9;
    int q = (s & 3) ^ ((s >> 3) & 3);
    int row = tb[m >> 5] * kT + (m & 31);
    size_t src = (size_t)row * kH + kblk * 64 + kk * 32 + q * 8;
    short8 v;
    if (fx) {
      float4 u = *(const float4*)(xf + src);
      float4 w = *(const float4*)(xf + src + 4);
      v[0] = f2bfb(u.x); v[1] = f2bfb(u.y); v[2] = f2bfb(u.z); v[3] = f2bfb(u.w);
      v[4] = f2bfb(w.x); v[5] = f2bfb(w.y); v[6] = f2bfb(w.z); v[7] = f2bfb(w.w);
    } else {
      v = *(const short8*)(xb + src);
    }
    dst[s] = v;
  }
}

// ---------------- GEMM1: h = gelu(x @ W1[e] + b1), hbuf in ffn2-A-staging order ----------------
__global__ __launch_bounds__(256, 2)
void k_ffn1(const __hip_bfloat16* __restrict__ xperm,
            const __hip_bfloat16* __restrict__ w1t,  // [E][F][H] bf16
            const __hip_bfloat16* __restrict__ b1,
            const int* __restrict__ tileExpert,
            const int* __restrict__ numTiles,
            int tileOff,
            __hip_bfloat16* __restrict__ hbuf) {
  int j = blockIdx.y;
  int local = j / 3;
  int tile = local + tileOff;
  if (tile >= *numTiles) return;
  int nIdx = 8 * (j % 3) + blockIdx.x;
  int nbase = nIdx * 128;
  int e = tileExpert[tile];
  __shared__ __align__(16) short ldsbuf[16384];   // A: [0,8192) B: [8192,16384)
  short* ldsA = ldsbuf;
  short* ldsB = ldsbuf + 8192;
  int tid = threadIdx.x;
  int lane = tid & 63, wid = tid >> 6;
  int wm = wid >> 1, wn = wid & 1;
  int lane16 = lane & 15, qf = lane >> 4;
  int swzl = (lane16 >> 1) & 3;
  int qx = (qf ^ swzl) * 8;

  f32x4 acc[4][4];
#pragma unroll
  for (int r = 0; r < 4; ++r)
#pragma unroll
    for (int c = 0; c < 4; ++c) acc[r][c] = (f32x4)0.f;

  const __hip_bfloat16* w1e = w1t + (size_t)e * kF * kH;
  const __hip_bfloat16* xtile = xperm + (size_t)tile * kXPermTile;
  const __hip_bfloat16* gB[4];
  short* lA[4];
  short* lB[4];
  int aoff[4];
#pragma unroll
  for (int it = 0; it < 4; ++it) {
    int s = it * 256 + tid;
    int m = (s >> 2) & 127, kk = s >> 9;
    int q = (s & 3) ^ ((s >> 3) & 3);
    aoff[it] = s * 8;
    gB[it] = w1e + (size_t)(nbase + m) * kH + kk * 32 + q * 8;
    lA[it] = &ldsA[s * 8];
    lB[it] = &ldsB[s * 8];
  }

  for (int k0 = 0; k0 < kH; k0 += 64) {
#pragma unroll
    for (int it = 0; it < 4; ++it) gld_lds16(xtile + k0 * 128 + aoff[it], lA[it]);
#pragma unroll
    for (int it = 0; it < 4; ++it) gld_lds16(gB[it] + k0, lB[it]);
    __syncthreads();
#pragma unroll
    for (int kk = 0; kk < 2; ++kk) {
      short8 af[4], bfr[4];
#pragma unroll
      for (int r = 0; r < 4; ++r) {
        int mr = wm * 64 + r * 16 + lane16;
        af[r] = *(const short8*)&ldsA[(kk * 512 + mr * 4) * 8 + qx];
      }
#pragma unroll
      for (int c = 0; c < 4; ++c) {
        int mb = wn * 64 + c * 16 + lane16;
        bfr[c] = *(const short8*)&ldsB[(kk * 512 + mb * 4) * 8 + qx];
      }
#pragma unroll
      for (int r = 0; r < 4; ++r)
#pragma unroll
        for (int c = 0; c < 4; ++c)
          acc[r][c] = __builtin_amdgcn_mfma_f32_16x16x32_bf16(af[r], bfr[c], acc[r][c], 0, 0, 0);
    }
    __syncthreads();
  }

  // epilogue: gelu(acc+bias) -> LDS in hbuf-staged order -> contiguous 16B global stores
  __hip_bfloat16* htile = hbuf + (size_t)local * kHbufTile;
  unsigned short* uls = (unsigned short*)ldsbuf;
  int q4 = qf * 4;
#pragma unroll
  for (int c = 0; c < 4; ++c) {
    int nn = wn * 64 + c * 16 + lane16;           // n - nbase in [0,128)
    float bias = bf2f(b1[e * kF + nbase + nn]);
    int lbase = (nn >> 6) * 8192 + ((nn >> 5) & 1) * 4096 + (nn & 7);
    int qn = (nn >> 3) & 3;
#pragma unroll
    for (int r = 0; r < 4; ++r) {
#pragma unroll
      for (int g = 0; g < 4; ++g) {
        int m = wm * 64 + r * 16 + q4 + g;
        float v = acc[r][c][g] + bias;
        uls[lbase + (m * 4 + (qn ^ ((m >> 1) & 3))) * 8] = f2bfb(gelu_f(v));
      }
    }
  }
  __syncthreads();
  unsigned short* dstg = (unsigned short*)htile + (size_t)(nbase >> 6) * 8192;
#pragma unroll
  for (int i = 0; i < 8; ++i) {
    int s = i * 2048 + tid * 8;
    *(short8*)(dstg + s) = *(const short8*)(uls + s);
  }
}

// ---------------- GEMM2: out = (h @ W2[e] + b2) * score, f32 scatter ----------------
__global__ __launch_bounds__(256, 2)
void k_ffn2(const __hip_bfloat16* __restrict__ hbuf,
            const __hip_bfloat16* __restrict__ w2t,  // [E][H][F] bf16
            const __hip_bfloat16* __restrict__ b2,
            const float* __restrict__ wsel,
            const int* __restrict__ tileExpert,
            const int* __restrict__ tileBatch,
            const int* __restrict__ numTiles,
            int tileOff, int chunk,
            float* __restrict__ out) {
  int j = blockIdx.y;
  int local = blockIdx.x + 8 * (j / 6);
  if (local >= chunk) return;
  int tile = local + tileOff;
  if (tile >= *numTiles) return;
  int nbase = (j % 6) * 128;
  int e = tileExpert[tile];
  int tbraw[4];
  float sc[4];
#pragma unroll
  for (int s = 0; s < 4; ++s) {
    int bb = tileBatch[tile * 4 + s];
    tbraw[s] = bb;
    sc[s] = (bb >= 0) ? wsel[bb] : 0.f;
  }
  __shared__ __align__(16) short ldsA[8192];
  __shared__ __align__(16) short ldsB[8192];
  int tid = threadIdx.x;
  int lane = tid & 63, wid = tid >> 6;
  int wm = wid >> 1, wn = wid & 1;
  int lane16 = lane & 15, qf = lane >> 4;
  int swzl = (lane16 >> 1) & 3;
  int qx = (qf ^ swzl) * 8;

  f32x4 acc[4][4];
#pragma unroll
  for (int r = 0; r < 4; ++r)
#pragma unroll
    for (int c = 0; c < 4; ++c) acc[r][c] = (f32x4)0.f;

  const __hip_bfloat16* w2e = w2t + (size_t)e * kF * kH;
  const __hip_bfloat16* htile = hbuf + (size_t)local * kHbufTile;
  const __hip_bfloat16* gB[4];
  short* lA[4];
  short* lB[4];
  int aoff[4];
#pragma unroll
  for (int it = 0; it < 4; ++it) {
    int s = it * 256 + tid;
    int m = (s >> 2) & 127, kk = s >> 9;
    int q = (s & 3) ^ ((s >> 3) & 3);
    aoff[it] = s * 8;
    gB[it] = w2e + (size_t)(nbase + m) * kF + kk * 32 + q * 8;
    lA[it] = &ldsA[s * 8];
    lB[it] = &ldsB[s * 8];
  }

  for (int k0 = 0; k0 < kF; k0 += 64) {
#pragma unroll
    for (int it = 0; it < 4; ++it) gld_lds16(htile + k0 * 128 + aoff[it], lA[it]);
#pragma unroll
    for (int it = 0; it < 4; ++it) gld_lds16(gB[it] + k0, lB[it]);
    __syncthreads();
#pragma unroll
    for (int kk = 0; kk < 2; ++kk) {
      short8 af[4], bfr[4];
#pragma unroll
      for (int r = 0; r < 4; ++r) {
        int mr = wm * 64 + r * 16 + lane16;
        af[r] = *(const short8*)&ldsA[(kk * 512 + mr * 4) * 8 + qx];
      }
#pragma unroll
      for (int c = 0; c < 4; ++c) {
        int mb = wn * 64 + c * 16 + lane16;
        bfr[c] = *(const short8*)&ldsB[(kk * 512 + mb * 4) * 8 + qx];
      }
#pragma unroll
      for (int r = 0; r < 4; ++r)
#pragma unroll
        for (int c = 0; c < 4; ++c)
          acc[r][c] = __builtin_amdgcn_mfma_f32_16x16x32_bf16(af[r], bfr[c], acc[r][c], 0, 0, 0);
    }
    __syncthreads();
  }

  int q4 = qf * 4;
#pragma unroll
  for (int c = 0; c < 4; ++c) {
    int ncol = wn * 64 + c * 16 + lane16;
    float bias = bf2f(b2[e * kH + nbase + ncol]);
#pragma unroll
    for (int r = 0; r < 4; ++r) {
      int s = (wm * 64 + r * 16) >> 5;
      int bb = tbraw[s];
      if (bb < 0) continue;
      float scale = sc[s];
#pragma unroll
      for (int g = 0; g < 4; ++g) {
        int m = wm * 64 + r * 16 + q4 + g;
        float v = (acc[r][c][g] + bias) * scale;
        out[((size_t)(bb * kT + (m & 31))) * kH + nbase + ncol] = v;
      }
    }
  }
}

}  // namespace

extern "C" void kernel_launch(void* const* d_in, const int* in_sizes, int n_in,
                              void* d_out, int out_size, void* d_ws, size_t ws_size,
                              hipStream_t stream) {
  (void)in_sizes; (void)n_in; (void)out_size;
  float* out = (float*)d_out;

  char* ws = (char*)d_ws;
  size_t off = 0;
  auto alloc = [&](size_t bytes) -> char* {
    char* p = ws + off;
    off = (off + bytes + 255) & ~(size_t)255;
    return p;
  };
  int*   flags      = (int*)alloc(16);      // x, Wg, W1, W2
  int*   cnt        = (int*)alloc(kE * 4);
  int*   ticket     = (int*)alloc(4);
  float* wsel       = (float*)alloc(kB * 4);
  int*   lists      = (int*)alloc((size_t)kE * kB * 4);
  int*   tileExpert = (int*)alloc(kMaxTiles * 4);
  int*   tileBatch  = (int*)alloc(kMaxTiles * 4 * 4);
  int*   numTiles   = (int*)alloc(4);
  __hip_bfloat16* w1t   = (__hip_bfloat16*)alloc((size_t)kE * kH * kF * 2);      // 14.2 MB
  __hip_bfloat16* w2t   = (__hip_bfloat16*)alloc((size_t)kE * kH * kF * 2);      // 14.2 MB
  __hip_bfloat16* xperm = (__hip_bfloat16*)alloc((size_t)kMaxTiles * kXPermTile * 2);  // 25.8 MB

  // adaptive hbuf chunk (deterministic in ws_size)
  size_t tileBytes = (size_t)kHbufTile * 2;  // 786432
  size_t avail = (ws_size > off + tileBytes) ? (ws_size - off) : tileBytes;
  int chunk = (int)(avail / tileBytes);
  if (chunk > kMaxChunk) chunk = kMaxChunk;
  if (chunk < 1) chunk = 1;
  __hip_bfloat16* hbuf = (__hip_bfloat16*)alloc((size_t)chunk * tileBytes);

  k_sniff_all<<<4, 256, 0, stream>>>((const unsigned short*)d_in[0],
                                     (const unsigned short*)d_in[1],
                                     (const unsigned short*)d_in[2],
                                     (const unsigned short*)d_in[4],
                                     flags, cnt, ticket);
  k_route<<<kB, 256, 0, stream>>>(d_in[0], d_in[1], flags, wsel, cnt, lists,
                                  ticket, tileExpert, tileBatch, numTiles);
  k_transpose6<<<dim3(576, 1, 6), 256, 0, stream>>>(d_in[2], d_in[4], w1t, w2t, flags);
  k_convert_x<<<dim3(kH / 64, kMaxTiles), 256, 0, stream>>>(d_in[0], flags, tileBatch,
                                                            numTiles, xperm);
  for (int toff = 0; toff < kMaxTiles; toff += chunk) {
    k_ffn1<<<dim3(8, 3 * chunk), 256, 0, stream>>>(xperm, w1t,
                                                   (const __hip_bfloat16*)d_in[3],
                                                   tileExpert, numTiles, toff, hbuf);
    int rows2 = (chunk + 7) / 8;
    k_ffn2<<<dim3(8, 6 * rows2), 256, 0, stream>>>(hbuf, w2t,
                                                   (const __hip_bfloat16*)d_in[5], wsel,
                                                   tileExpert, tileBatch, numTiles,
                                                   toff, chunk, out);
  }
}

// Round 2
// 425.965 us; speedup vs baseline: 1.0084x; 1.0084x over previous
//
#include <hip/hip_runtime.h>
#include <hip/hip_bf16.h>
#include <cstdint>
#include <cstddef>

namespace {

constexpr int kB = 512, kT = 32, kH = 768, kF = 3072, kE = 3;
constexpr int kMaxTiles = 132;   // sum 2*ceil(cnt_e/8) <= 132 (pairs, expert-uniform)
constexpr int kMaxChunk = 132;
constexpr int kXPermTile = 128 * kH;   // 98304 elts per tile
constexpr int kHbufTile  = 128 * kF;   // 393216 elts per tile
constexpr int kNT2 = kF / 32;          // 96 K-tiles for ffn2 8-phase pipeline

typedef __attribute__((ext_vector_type(8))) short short8;
typedef __attribute__((ext_vector_type(4))) float f32x4;

__device__ __forceinline__ void gld_lds16(const void* g, void* l) {
  __builtin_amdgcn_global_load_lds(
      (const __attribute__((address_space(1))) void*)g,
      (__attribute__((address_space(3))) void*)l, 16, 0, 0);
}

__device__ __forceinline__ float bf2f(__hip_bfloat16 v) { return __bfloat162float(v); }
__device__ __forceinline__ float bfu(unsigned short u) {
  return __uint_as_float(((unsigned)u) << 16);
}
__device__ __forceinline__ unsigned short f2bfb(float f) {
  __hip_bfloat16 h = __float2bfloat16(f);
  return *reinterpret_cast<unsigned short*>(&h);
}

// exact-grade gelu: Abramowitz-Stegun 7.1.26 erf, |err| <= 1.5e-7
__device__ __forceinline__ float gelu_f(float v) {
  float av = fabsf(v);
  float z = av * 0.70710678118654752f;
  float t = __builtin_amdgcn_rcpf(fmaf(0.3275911f, z, 1.0f));
  float p = fmaf(fmaf(fmaf(fmaf(1.061405429f, t, -1.453152027f), t, 1.421413741f),
                      t, -0.284496736f), t, 0.254829592f) * t;
  float er = fmaf(-p, __expf(-z * z), 1.0f);   // erf(z), z >= 0
  return 0.5f * v + 0.5f * av * er;
}

// ---- fused per-tensor dtype sniff (4 blocks) + workspace re-init ----
__global__ void k_sniff_all(const unsigned short* __restrict__ x,
                            const unsigned short* __restrict__ g,
                            const unsigned short* __restrict__ w1,
                            const unsigned short* __restrict__ w2,
                            int* __restrict__ flags, int* __restrict__ cnt,
                            int* __restrict__ ticket) {
  int bb = blockIdx.x;
  if (bb == 0 && threadIdx.x < 4) {
    if (threadIdx.x < 3) cnt[threadIdx.x] = 0;
    else *ticket = 0;
  }
  const unsigned short* p = (bb == 0) ? x : (bb == 1) ? g : (bb == 2) ? w1 : w2;
  int nwords = (bb == 1) ? kE * kH : 4096;
  __shared__ int cnt_s;
  if (threadIdx.x == 0) cnt_s = 0;
  __syncthreads();
  int local = 0;
  for (int i = threadIdx.x; i < nwords; i += 256) {
    unsigned e = (p[i] >> 7) & 0xFF;
    if (e >= 0xC0) ++local;
  }
  atomicAdd(&cnt_s, local);
  __syncthreads();
  if (threadIdx.x == 0) flags[bb] = (cnt_s > 64) ? 1 : 0;
}

// ---------------- routing (vectorized) + tile packing in last block ----------------
__global__ void k_route(const void* __restrict__ xv, const void* __restrict__ Wgv,
                        const int* __restrict__ flags,
                        float* __restrict__ wsel,
                        int* __restrict__ cnt, int* __restrict__ lists,
                        int* __restrict__ ticket,
                        int* __restrict__ tileExpert, int* __restrict__ tileBatch,
                        int* __restrict__ numTiles) {
  bool fx = (flags[0] != 0), fg = (flags[1] != 0);
  int b = blockIdx.x;
  int tid = threadIdx.x;
  float a0 = 0.f, a1 = 0.f, a2 = 0.f;
  if (tid < 192) {   // 192 * float4 = 768 h
    float m0 = 0.f, m1 = 0.f, m2 = 0.f, m3 = 0.f;
    if (fx) {
      const float4* xr = (const float4*)((const float*)xv + (size_t)b * kT * kH) + tid;
#pragma unroll 8
      for (int t = 0; t < kT; ++t) {
        float4 u = xr[t * 192];
        m0 += u.x; m1 += u.y; m2 += u.z; m3 += u.w;
      }
    } else {
      const ushort4* xr = (const ushort4*)((const unsigned short*)xv + (size_t)b * kT * kH) + tid;
#pragma unroll 8
      for (int t = 0; t < kT; ++t) {
        ushort4 u = xr[t * 192];
        m0 += bfu(u.x); m1 += bfu(u.y); m2 += bfu(u.z); m3 += bfu(u.w);
      }
    }
    const float inv = 1.f / kT;
    m0 *= inv; m1 *= inv; m2 *= inv; m3 *= inv;
#pragma unroll
    for (int e = 0; e < kE; ++e) {
      float w0, w1v, w2v, w3;
      int base = e * kH + tid * 4;
      if (fg) {
        float4 u = *(const float4*)((const float*)Wgv + base);
        w0 = u.x; w1v = u.y; w2v = u.z; w3 = u.w;
      } else {
        ushort4 u = *(const ushort4*)((const unsigned short*)Wgv + base);
        w0 = bfu(u.x); w1v = bfu(u.y); w2v = bfu(u.z); w3 = bfu(u.w);
      }
      float d = m0 * w0 + m1 * w1v + m2 * w2v + m3 * w3;
      if (e == 0) a0 = d; else if (e == 1) a1 = d; else a2 = d;
    }
  }
  __shared__ float red[3][256];
  red[0][tid] = a0; red[1][tid] = a1; red[2][tid] = a2;
  __syncthreads();
  for (int s2 = 128; s2 > 0; s2 >>= 1) {
    if (tid < s2) {
      red[0][tid] += red[0][tid + s2];
      red[1][tid] += red[1][tid + s2];
      red[2][tid] += red[2][tid + s2];
    }
    __syncthreads();
  }
  if (tid == 0) {
    float l0 = red[0][0], l1 = red[1][0], l2 = red[2][0];
    int am = 0; float mx = l0;
    if (l1 > mx) { mx = l1; am = 1; }
    if (l2 > mx) { mx = l2; am = 2; }
    float e0 = expf(l0 - mx), e1 = expf(l1 - mx), e2 = expf(l2 - mx);
    float inv = 1.f / (e0 + e1 + e2);
    float sc = (am == 0 ? e0 : (am == 1 ? e1 : e2)) * inv;
    wsel[b] = sc;
    int pos = atomicAdd(&cnt[am], 1);
    lists[am * kB + pos] = b;
    __threadfence();                       // publish lists/cnt (release)
    int tk = atomicAdd(ticket, 1);
    if (tk == kB - 1) {                    // last block packs the tiles
      __threadfence();                     // acquire side
      int t = 0;
      for (int e = 0; e < kE; ++e) {
        int c = cnt[e];
        int cpad = (c + 7) & ~7;           // pad to 8 batches -> expert-uniform PAIRS of tiles
        for (int i = 0; i < cpad; i += 4) {
          tileExpert[t] = e;
          for (int s = 0; s < 4; ++s)
            tileBatch[t * 4 + s] = (i + s < c) ? lists[e * kB + i + s] : -1;
          ++t;
        }
      }
      *numTiles = t;                       // even, pairs expert-uniform
      for (int tt = t; tt < kMaxTiles; ++tt) {
        tileExpert[tt] = 0;
        for (int s = 0; s < 4; ++s) tileBatch[tt * 4 + s] = -1;
      }
    }
  }
}

// ---------------- fused transpose + convert: both weight tensors, one launch ----------------
__global__ __launch_bounds__(256)
void k_transpose6(const void* __restrict__ w1src, const void* __restrict__ w2src,
                  __hip_bfloat16* __restrict__ w1dst, __hip_bfloat16* __restrict__ w2dst,
                  const int* __restrict__ flags) {
  int z = blockIdx.z;
  bool isW1 = (z < 3);
  int e = isW1 ? z : z - 3;
  bool f32 = (flags[isW1 ? 2 : 3] != 0);
  const float* sf = (const float*)(isW1 ? w1src : w2src);
  const unsigned short* sb = (const unsigned short*)(isW1 ? w1src : w2src);
  unsigned short* dst = (unsigned short*)(isW1 ? w1dst : w2dst);
  int K = isW1 ? kH : kF, N = isW1 ? kF : kH;
  int ntx = N / 64;
  int bx = blockIdx.x;
  int n0 = (bx % ntx) * 64, k0 = (bx / ntx) * 64;
  __shared__ __align__(16) unsigned short t[64][73];
  size_t eoff = (size_t)e * K * N;
  int tr = threadIdx.x >> 4;
  int tc4 = (threadIdx.x & 15) * 4;
#pragma unroll
  for (int i = 0; i < 4; ++i) {
    int r = tr + 16 * i;
    size_t idx = eoff + (size_t)(k0 + r) * N + n0 + tc4;
    if (f32) {
      float4 u = *(const float4*)(sf + idx);
      t[r][tc4] = f2bfb(u.x); t[r][tc4 + 1] = f2bfb(u.y);
      t[r][tc4 + 2] = f2bfb(u.z); t[r][tc4 + 3] = f2bfb(u.w);
    } else {
      ushort4 u = *(const ushort4*)(sb + idx);
      t[r][tc4] = u.x; t[r][tc4 + 1] = u.y; t[r][tc4 + 2] = u.z; t[r][tc4 + 3] = u.w;
    }
  }
  __syncthreads();
#pragma unroll
  for (int i = 0; i < 4; ++i) {
    int rn = tr + 16 * i;
    ushort4 v;
    v.x = t[tc4][rn]; v.y = t[tc4 + 1][rn]; v.z = t[tc4 + 2][rn]; v.w = t[tc4 + 3][rn];
    *(ushort4*)(dst + eoff + (size_t)(n0 + rn) * K + k0 + tc4) = v;
  }
}

// ---------------- convert + permute x into ffn1 A-staging order ----------------
__global__ __launch_bounds__(256)
void k_convert_x(const void* __restrict__ xv, const int* __restrict__ flags,
                 const int* __restrict__ tileBatch, const int* __restrict__ numTiles,
                 __hip_bfloat16* __restrict__ xperm) {
  int tile = blockIdx.y;
  if (tile >= *numTiles) return;
  int kblk = blockIdx.x;
  bool fx = (flags[0] != 0);
  const float* xf = (const float*)xv;
  const __hip_bfloat16* xb = (const __hip_bfloat16*)xv;
  int tb0 = tileBatch[tile * 4];
  int tb[4];
#pragma unroll
  for (int s = 0; s < 4; ++s) {
    int bb = tileBatch[tile * 4 + s];
    tb[s] = (bb < 0) ? ((tb0 < 0) ? 0 : tb0) : bb;
  }
  int tid = threadIdx.x;
  short8* dst = (short8*)(xperm + (size_t)tile * kXPermTile + kblk * 8192);
#pragma unroll
  for (int i = 0; i < 4; ++i) {
    int s = i * 256 + tid;
    int m = (s >> 2) & 127, kk = s >> 9;
    int q = (s & 3) ^ ((s >> 3) & 3);
    int row = tb[m >> 5] * kT + (m & 31);
    size_t src = (size_t)row * kH + kblk * 64 + kk * 32 + q * 8;
    short8 v;
    if (fx) {
      float4 u = *(const float4*)(xf + src);
      float4 w = *(const float4*)(xf + src + 4);
      v[0] = f2bfb(u.x); v[1] = f2bfb(u.y); v[2] = f2bfb(u.z); v[3] = f2bfb(u.w);
      v[4] = f2bfb(w.x); v[5] = f2bfb(w.y); v[6] = f2bfb(w.z); v[7] = f2bfb(w.w);
    } else {
      v = *(const short8*)(xb + src);
    }
    dst[s] = v;
  }
}

// ---------------- GEMM1: h = gelu(x @ W1[e] + b1), hbuf in ffn2-A-staging order ----------------
// unchanged 128x128 2-phase structure (clean A/B vs new ffn2)
__global__ __launch_bounds__(256, 2)
void k_ffn1(const __hip_bfloat16* __restrict__ xperm,
            const __hip_bfloat16* __restrict__ w1t,  // [E][F][H] bf16
            const __hip_bfloat16* __restrict__ b1,
            const int* __restrict__ tileExpert,
            const int* __restrict__ numTiles,
            int tileOff,
            __hip_bfloat16* __restrict__ hbuf) {
  int j = blockIdx.y;
  int local = j / 3;
  int tile = local + tileOff;
  if (tile >= *numTiles) return;
  int nIdx = 8 * (j % 3) + blockIdx.x;
  int nbase = nIdx * 128;
  int e = tileExpert[tile];
  __shared__ __align__(16) short ldsbuf[16384];   // A: [0,8192) B: [8192,16384)
  short* ldsA = ldsbuf;
  short* ldsB = ldsbuf + 8192;
  int tid = threadIdx.x;
  int lane = tid & 63, wid = tid >> 6;
  int wm = wid >> 1, wn = wid & 1;
  int lane16 = lane & 15, qf = lane >> 4;
  int swzl = (lane16 >> 1) & 3;
  int qx = (qf ^ swzl) * 8;

  f32x4 acc[4][4];
#pragma unroll
  for (int r = 0; r < 4; ++r)
#pragma unroll
    for (int c = 0; c < 4; ++c) acc[r][c] = (f32x4)0.f;

  const __hip_bfloat16* w1e = w1t + (size_t)e * kF * kH;
  const __hip_bfloat16* xtile = xperm + (size_t)tile * kXPermTile;
  const __hip_bfloat16* gB[4];
  short* lA[4];
  short* lB[4];
  int aoff[4];
#pragma unroll
  for (int it = 0; it < 4; ++it) {
    int s = it * 256 + tid;
    int m = (s >> 2) & 127, kk = s >> 9;
    int q = (s & 3) ^ ((s >> 3) & 3);
    aoff[it] = s * 8;
    gB[it] = w1e + (size_t)(nbase + m) * kH + kk * 32 + q * 8;
    lA[it] = &ldsA[s * 8];
    lB[it] = &ldsB[s * 8];
  }

  for (int k0 = 0; k0 < kH; k0 += 64) {
#pragma unroll
    for (int it = 0; it < 4; ++it) gld_lds16(xtile + k0 * 128 + aoff[it], lA[it]);
#pragma unroll
    for (int it = 0; it < 4; ++it) gld_lds16(gB[it] + k0, lB[it]);
    __syncthreads();
#pragma unroll
    for (int kk = 0; kk < 2; ++kk) {
      short8 af[4], bfr[4];
#pragma unroll
      for (int r = 0; r < 4; ++r) {
        int mr = wm * 64 + r * 16 + lane16;
        af[r] = *(const short8*)&ldsA[(kk * 512 + mr * 4) * 8 + qx];
      }
#pragma unroll
      for (int c = 0; c < 4; ++c) {
        int mb = wn * 64 + c * 16 + lane16;
        bfr[c] = *(const short8*)&ldsB[(kk * 512 + mb * 4) * 8 + qx];
      }
#pragma unroll
      for (int r = 0; r < 4; ++r)
#pragma unroll
        for (int c = 0; c < 4; ++c)
          acc[r][c] = __builtin_amdgcn_mfma_f32_16x16x32_bf16(af[r], bfr[c], acc[r][c], 0, 0, 0);
    }
    __syncthreads();
  }

  // epilogue: gelu(acc+bias) -> LDS in hbuf-staged order -> contiguous 16B global stores
  __hip_bfloat16* htile = hbuf + (size_t)local * kHbufTile;
  unsigned short* uls = (unsigned short*)ldsbuf;
  int q4 = qf * 4;
#pragma unroll
  for (int c = 0; c < 4; ++c) {
    int nn = wn * 64 + c * 16 + lane16;           // n - nbase in [0,128)
    float bias = bf2f(b1[e * kF + nbase + nn]);
    int lbase = (nn >> 6) * 8192 + ((nn >> 5) & 1) * 4096 + (nn & 7);
    int qn = (nn >> 3) & 3;
#pragma unroll
    for (int r = 0; r < 4; ++r) {
#pragma unroll
      for (int g = 0; g < 4; ++g) {
        int m = wm * 64 + r * 16 + q4 + g;
        float v = acc[r][c][g] + bias;
        uls[lbase + (m * 4 + (qn ^ ((m >> 1) & 3))) * 8] = f2bfb(gelu_f(v));
      }
    }
  }
  __syncthreads();
  unsigned short* dstg = (unsigned short*)htile + (size_t)(nbase >> 6) * 8192;
#pragma unroll
  for (int i = 0; i < 8; ++i) {
    int s = i * 2048 + tid * 8;
    *(short8*)(dstg + s) = *(const short8*)(uls + s);
  }
}

// ---------------- GEMM2 (8-phase 256x256, BK=32, 4-slot LDS ring, counted vmcnt) ----------------
// out = (h @ W2[e] + b2) * score, f32 scatter.
// 512 threads = 8 waves (2M x 4N), per-wave 128x64 output, acc[8][4].
// LDS: 4 slots x 32KB {A0,A1,B0,B1 halves of one 32-K tile}; stage 3 K-tiles ahead,
// vmcnt(8) at group boundaries (loads stay in flight across barriers - T3+T4), T5 setprio.
__global__ __launch_bounds__(512, 2)
void k_ffn2(const __hip_bfloat16* __restrict__ hbuf,
            const __hip_bfloat16* __restrict__ w2t,  // [E][H][F] bf16
            const __hip_bfloat16* __restrict__ b2,
            const float* __restrict__ wsel,
            const int* __restrict__ tileExpert,
            const int* __restrict__ tileBatch,
            const int* __restrict__ numTiles,
            int tileOff, int chunk,
            float* __restrict__ out) {
  extern __shared__ __align__(16) short lds[];     // 65536 shorts = 128 KiB
  int nblk = (chunk >> 1) * 3;
  int lid = blockIdx.x * gridDim.y + blockIdx.y;   // XCD-chunked linear id
  if (lid >= nblk) return;
  int pair = lid / 3;
  int nbase = (lid - pair * 3) * 256;
  int tile0 = tileOff + 2 * pair;
  if (tile0 >= *numTiles) return;
  int e = tileExpert[tile0];                       // pair is expert-uniform

  int tbraw[8];
  float sc[8];
#pragma unroll
  for (int s = 0; s < 8; ++s) {
    int bb = tileBatch[tile0 * 4 + s];
    tbraw[s] = bb;
    sc[s] = (bb >= 0) ? wsel[bb] : 0.f;
  }

  int tid = threadIdx.x;                 // 0..511
  int lane = tid & 63, wid = tid >> 6;
  int wm = wid >> 2, wn = wid & 3;       // 2M x 4N waves
  int lane16 = lane & 15, qf = lane >> 4;
  int qx = (qf ^ ((lane16 >> 1) & 3)) * 8;
  int tid8 = tid * 8;                    // stage LDS offset (shorts)

  // staging source addressing (per-lane pre-swizzled global, linear LDS dest)
  int sm = tid >> 2;                               // 0..127
  int sq = (tid & 3) ^ ((tid >> 3) & 3);
  const __hip_bfloat16* w2e = w2t + (size_t)e * kF * kH;
  const __hip_bfloat16* aS0 = hbuf + (size_t)(2 * pair) * kHbufTile + tid8;
  const __hip_bfloat16* aS1 = hbuf + (size_t)(2 * pair + 1) * kHbufTile + tid8;
  const __hip_bfloat16* bS0 = w2e + (size_t)(nbase + sm) * kF + sq * 8;
  const __hip_bfloat16* bS1 = w2e + (size_t)(nbase + 128 + sm) * kF + sq * 8;

  // fragment read offsets within a slot (shorts)
  int aOffB = wm * 4096 + lane16 * 32 + qx;
  int bOffB = 8192 + (wn >> 1) * 4096 + (wn & 1) * 2048 + lane16 * 32 + qx;

  f32x4 acc[8][4];
#pragma unroll
  for (int r = 0; r < 8; ++r)
#pragma unroll
    for (int c = 0; c < 4; ++c) acc[r][c] = (f32x4)0.f;

  // prologue: stage K-tiles 0,1,2 into slots 0,1,2
#pragma unroll
  for (int kt = 0; kt < 3; ++kt) {
    int sl = kt * 16384;
    gld_lds16(aS0 + (size_t)kt * 4096, &lds[sl + tid8]);
    gld_lds16(aS1 + (size_t)kt * 4096, &lds[sl + 4096 + tid8]);
    gld_lds16(bS0 + kt * 32, &lds[sl + 8192 + tid8]);
    gld_lds16(bS1 + kt * 32, &lds[sl + 12288 + tid8]);
  }
  asm volatile("s_waitcnt vmcnt(8)" ::: "memory");   // K-tile 0 landed (my wave)
  __builtin_amdgcn_s_barrier();                       // all waves' too

  for (int t = 0; t < kNT2; ++t) {
    short* sb = &lds[(t & 3) * 16384];
    const int g3 = t + 3;
    // ---- phase A: rows 0..63 of wave tile ----
    short8 a0 = *(const short8*)&sb[aOffB + 0 * 512];
    short8 a1 = *(const short8*)&sb[aOffB + 1 * 512];
    short8 a2 = *(const short8*)&sb[aOffB + 2 * 512];
    short8 a3 = *(const short8*)&sb[aOffB + 3 * 512];
    short8 b0 = *(const short8*)&sb[bOffB + 0 * 512];
    short8 b1 = *(const short8*)&sb[bOffB + 1 * 512];
    short8 b2v = *(const short8*)&sb[bOffB + 2 * 512];
    short8 b3 = *(const short8*)&sb[bOffB + 3 * 512];
    if (g3 < kNT2) {                                 // stage A halves of kt t+3
      int sl = (g3 & 3) * 16384;
      gld_lds16(aS0 + (size_t)g3 * 4096, &lds[sl + tid8]);
      gld_lds16(aS1 + (size_t)g3 * 4096, &lds[sl + 4096 + tid8]);
    }
    __builtin_amdgcn_s_barrier();
    __builtin_amdgcn_s_setprio(1);
#pragma unroll
    for (int r = 0; r < 4; ++r) {
      short8 ar = (r == 0) ? a0 : (r == 1) ? a1 : (r == 2) ? a2 : a3;
      acc[r][0] = __builtin_amdgcn_mfma_f32_16x16x32_bf16(ar, b0, acc[r][0], 0, 0, 0);
      acc[r][1] = __builtin_amdgcn_mfma_f32_16x16x32_bf16(ar, b1, acc[r][1], 0, 0, 0);
      acc[r][2] = __builtin_amdgcn_mfma_f32_16x16x32_bf16(ar, b2v, acc[r][2], 0, 0, 0);
      acc[r][3] = __builtin_amdgcn_mfma_f32_16x16x32_bf16(ar, b3, acc[r][3], 0, 0, 0);
    }
    __builtin_amdgcn_s_setprio(0);
    __builtin_amdgcn_s_barrier();
    // ---- phase B: rows 64..127 of wave tile ----
    a0 = *(const short8*)&sb[aOffB + 4 * 512];
    a1 = *(const short8*)&sb[aOffB + 5 * 512];
    a2 = *(const short8*)&sb[aOffB + 6 * 512];
    a3 = *(const short8*)&sb[aOffB + 7 * 512];
    if (g3 < kNT2) {                                 // stage B halves of kt t+3
      int sl = (g3 & 3) * 16384;
      gld_lds16(bS0 + g3 * 32, &lds[sl + 8192 + tid8]);
      gld_lds16(bS1 + g3 * 32, &lds[sl + 12288 + tid8]);
    }
    // group-boundary wait for K-tile t+1 (counted; only drains at the very tail)
    if (t < kNT2 - 3)       { asm volatile("s_waitcnt vmcnt(8)" ::: "memory"); }
    else if (t == kNT2 - 3) { asm volatile("s_waitcnt vmcnt(4)" ::: "memory"); }
    else if (t == kNT2 - 2) { asm volatile("s_waitcnt vmcnt(0)" ::: "memory"); }
    __builtin_amdgcn_s_barrier();
    __builtin_amdgcn_s_setprio(1);
#pragma unroll
    for (int r = 0; r < 4; ++r) {
      short8 ar = (r == 0) ? a0 : (r == 1) ? a1 : (r == 2) ? a2 : a3;
      acc[r + 4][0] = __builtin_amdgcn_mfma_f32_16x16x32_bf16(ar, b0, acc[r + 4][0], 0, 0, 0);
      acc[r + 4][1] = __builtin_amdgcn_mfma_f32_16x16x32_bf16(ar, b1, acc[r + 4][1], 0, 0, 0);
      acc[r + 4][2] = __builtin_amdgcn_mfma_f32_16x16x32_bf16(ar, b2v, acc[r + 4][2], 0, 0, 0);
      acc[r + 4][3] = __builtin_amdgcn_mfma_f32_16x16x32_bf16(ar, b3, acc[r + 4][3], 0, 0, 0);
    }
    __builtin_amdgcn_s_setprio(0);
    __builtin_amdgcn_s_barrier();
  }

  // epilogue: scatter f32 (skip padded batches)
  int q4 = qf * 4;
#pragma unroll
  for (int c = 0; c < 4; ++c) {
    int ncol = nbase + wn * 64 + c * 16 + lane16;
    float bias = bf2f(b2[e * kH + ncol]);
#pragma unroll
    for (int r = 0; r < 8; ++r) {
      int mbase = wm * 128 + r * 16;
      int s = mbase >> 5;
      int bb = tbraw[s];
      if (bb < 0) continue;
      float scale = sc[s];
#pragma unroll
      for (int g = 0; g < 4; ++g) {
        int m = mbase + q4 + g;
        float v = (acc[r][c][g] + bias) * scale;
        out[((size_t)(bb * kT + (m & 31))) * kH + ncol] = v;
      }
    }
  }
}

}  // namespace

extern "C" void kernel_launch(void* const* d_in, const int* in_sizes, int n_in,
                              void* d_out, int out_size, void* d_ws, size_t ws_size,
                              hipStream_t stream) {
  (void)in_sizes; (void)n_in; (void)out_size;
  float* out = (float*)d_out;

  char* ws = (char*)d_ws;
  size_t off = 0;
  auto alloc = [&](size_t bytes) -> char* {
    char* p = ws + off;
    off = (off + bytes + 255) & ~(size_t)255;
    return p;
  };
  int*   flags      = (int*)alloc(16);      // x, Wg, W1, W2
  int*   cnt        = (int*)alloc(kE * 4);
  int*   ticket     = (int*)alloc(4);
  float* wsel       = (float*)alloc(kB * 4);
  int*   lists      = (int*)alloc((size_t)kE * kB * 4);
  int*   tileExpert = (int*)alloc(kMaxTiles * 4);
  int*   tileBatch  = (int*)alloc(kMaxTiles * 4 * 4);
  int*   numTiles   = (int*)alloc(4);
  __hip_bfloat16* w1t   = (__hip_bfloat16*)alloc((size_t)kE * kH * kF * 2);      // 14.2 MB
  __hip_bfloat16* w2t   = (__hip_bfloat16*)alloc((size_t)kE * kH * kF * 2);      // 14.2 MB
  __hip_bfloat16* xperm = (__hip_bfloat16*)alloc((size_t)kMaxTiles * kXPermTile * 2);  // 26 MB

  // adaptive hbuf chunk (deterministic in ws_size); must be EVEN (ffn2 works on pairs)
  size_t tileBytes = (size_t)kHbufTile * 2;  // 786432
  size_t avail = (ws_size > off + 2 * tileBytes) ? (ws_size - off) : 2 * tileBytes;
  int chunk = (int)(avail / tileBytes);
  if (chunk > kMaxChunk) chunk = kMaxChunk;
  chunk &= ~1;
  if (chunk < 2) chunk = 2;
  __hip_bfloat16* hbuf = (__hip_bfloat16*)alloc((size_t)chunk * tileBytes);

  // allow 128 KiB dynamic LDS for the 8-phase ffn2
  static bool attrDone = false;
  if (!attrDone) {
    hipFuncSetAttribute((const void*)k_ffn2,
                        hipFuncAttributeMaxDynamicSharedMemorySize, 131072);
    attrDone = true;
  }

  k_sniff_all<<<4, 256, 0, stream>>>((const unsigned short*)d_in[0],
                                     (const unsigned short*)d_in[1],
                                     (const unsigned short*)d_in[2],
                                     (const unsigned short*)d_in[4],
                                     flags, cnt, ticket);
  k_route<<<kB, 256, 0, stream>>>(d_in[0], d_in[1], flags, wsel, cnt, lists,
                                  ticket, tileExpert, tileBatch, numTiles);
  k_transpose6<<<dim3(576, 1, 6), 256, 0, stream>>>(d_in[2], d_in[4], w1t, w2t, flags);
  k_convert_x<<<dim3(kH / 64, kMaxTiles), 256, 0, stream>>>(d_in[0], flags, tileBatch,
                                                            numTiles, xperm);
  for (int toff = 0; toff < kMaxTiles; toff += chunk) {
    k_ffn1<<<dim3(8, 3 * chunk), 256, 0, stream>>>(xperm, w1t,
                                                   (const __hip_bfloat16*)d_in[3],
                                                   tileExpert, numTiles, toff, hbuf);
    int nblk2 = (chunk / 2) * 3;
    k_ffn2<<<dim3(8, (nblk2 + 7) / 8), 512, 131072, stream>>>(
        hbuf, w2t, (const __hip_bfloat16*)d_in[5], wsel,
        tileExpert, tileBatch, numTiles, toff, chunk, out);
  }
}

// Round 4
// 412.985 us; speedup vs baseline: 1.0401x; 1.0314x over previous
//
#include <hip/hip_runtime.h>
#include <hip/hip_bf16.h>
#include <cstdint>
#include <cstddef>

namespace {

constexpr int kB = 512, kT = 32, kH = 768, kF = 3072, kE = 3;
constexpr int kMaxTiles = 132;   // sum 2*ceil(cnt_e/8) <= 132 (pairs, expert-uniform)
constexpr int kMaxChunk = 132;
constexpr int kHbufPair = 96 * 8192;   // 786432 elts per PAIR (= ffn2 A-staging stream)
constexpr int kNT1 = kH / 32;          // 24 K-tiles for ffn1
constexpr int kNT2 = kF / 32;          // 96 K-tiles for ffn2

typedef __attribute__((ext_vector_type(8))) short short8;
typedef __attribute__((ext_vector_type(4))) float f32x4;

__device__ __forceinline__ void gld_lds16(const void* g, void* l) {
  __builtin_amdgcn_global_load_lds(
      (const __attribute__((address_space(1))) void*)g,
      (__attribute__((address_space(3))) void*)l, 16, 0, 0);
}

__device__ __forceinline__ float bf2f(__hip_bfloat16 v) { return __bfloat162float(v); }
__device__ __forceinline__ float bfu(unsigned short u) {
  return __uint_as_float(((unsigned)u) << 16);
}
__device__ __forceinline__ unsigned short f2bfb(float f) {
  __hip_bfloat16 h = __float2bfloat16(f);
  return *reinterpret_cast<unsigned short*>(&h);
}

// exact-grade gelu: Abramowitz-Stegun 7.1.26 erf, |err| <= 1.5e-7
__device__ __forceinline__ float gelu_f(float v) {
  float av = fabsf(v);
  float z = av * 0.70710678118654752f;
  float t = __builtin_amdgcn_rcpf(fmaf(0.3275911f, z, 1.0f));
  float p = fmaf(fmaf(fmaf(fmaf(1.061405429f, t, -1.453152027f), t, 1.421413741f),
                      t, -0.284496736f), t, 0.254829592f) * t;
  float er = fmaf(-p, __expf(-z * z), 1.0f);   // erf(z), z >= 0
  return 0.5f * v + 0.5f * av * er;
}

// ---- fused per-tensor dtype sniff (4 blocks) + workspace re-init ----
__global__ void k_sniff_all(const unsigned short* __restrict__ x,
                            const unsigned short* __restrict__ g,
                            const unsigned short* __restrict__ w1,
                            const unsigned short* __restrict__ w2,
                            int* __restrict__ flags, int* __restrict__ cnt,
                            int* __restrict__ ticket) {
  int bb = blockIdx.x;
  if (bb == 0 && threadIdx.x < 4) {
    if (threadIdx.x < 3) cnt[threadIdx.x] = 0;
    else *ticket = 0;
  }
  const unsigned short* p = (bb == 0) ? x : (bb == 1) ? g : (bb == 2) ? w1 : w2;
  int nwords = (bb == 1) ? kE * kH : 4096;
  __shared__ int cnt_s;
  if (threadIdx.x == 0) cnt_s = 0;
  __syncthreads();
  int local = 0;
  for (int i = threadIdx.x; i < nwords; i += 256) {
    unsigned e = (p[i] >> 7) & 0xFF;
    if (e >= 0xC0) ++local;
  }
  atomicAdd(&cnt_s, local);
  __syncthreads();
  if (threadIdx.x == 0) flags[bb] = (cnt_s > 64) ? 1 : 0;
}

// ---------------- routing + parallel tile packing in last block ----------------
__global__ void k_route(const void* __restrict__ xv, const void* __restrict__ Wgv,
                        const int* __restrict__ flags,
                        float* __restrict__ wsel,
                        int* __restrict__ cnt, int* __restrict__ lists,
                        int* __restrict__ ticket,
                        int* __restrict__ tileExpert, int* __restrict__ tileBatch,
                        int* __restrict__ numTiles) {
  bool fx = (flags[0] != 0), fg = (flags[1] != 0);
  int b = blockIdx.x;
  int tid = threadIdx.x;
  float a0 = 0.f, a1 = 0.f, a2 = 0.f;
  if (tid < 192) {   // 192 * float4 = 768 h
    float m0 = 0.f, m1 = 0.f, m2 = 0.f, m3 = 0.f;
    if (fx) {
      const float4* xr = (const float4*)((const float*)xv + (size_t)b * kT * kH) + tid;
#pragma unroll 8
      for (int t = 0; t < kT; ++t) {
        float4 u = xr[t * 192];
        m0 += u.x; m1 += u.y; m2 += u.z; m3 += u.w;
      }
    } else {
      const ushort4* xr = (const ushort4*)((const unsigned short*)xv + (size_t)b * kT * kH) + tid;
#pragma unroll 8
      for (int t = 0; t < kT; ++t) {
        ushort4 u = xr[t * 192];
        m0 += bfu(u.x); m1 += bfu(u.y); m2 += bfu(u.z); m3 += bfu(u.w);
      }
    }
    const float inv = 1.f / kT;
    m0 *= inv; m1 *= inv; m2 *= inv; m3 *= inv;
#pragma unroll
    for (int e = 0; e < kE; ++e) {
      float w0, w1v, w2v, w3;
      int base = e * kH + tid * 4;
      if (fg) {
        float4 u = *(const float4*)((const float*)Wgv + base);
        w0 = u.x; w1v = u.y; w2v = u.z; w3 = u.w;
      } else {
        ushort4 u = *(const ushort4*)((const unsigned short*)Wgv + base);
        w0 = bfu(u.x); w1v = bfu(u.y); w2v = bfu(u.z); w3 = bfu(u.w);
      }
      float d = m0 * w0 + m1 * w1v + m2 * w2v + m3 * w3;
      if (e == 0) a0 = d; else if (e == 1) a1 = d; else a2 = d;
    }
  }
  __shared__ float red[3][256];
  __shared__ int lastFlag;
  __shared__ int csh[3];
  red[0][tid] = a0; red[1][tid] = a1; red[2][tid] = a2;
  __syncthreads();
  for (int s2 = 128; s2 > 0; s2 >>= 1) {
    if (tid < s2) {
      red[0][tid] += red[0][tid + s2];
      red[1][tid] += red[1][tid + s2];
      red[2][tid] += red[2][tid + s2];
    }
    __syncthreads();
  }
  if (tid == 0) {
    float l0 = red[0][0], l1 = red[1][0], l2 = red[2][0];
    int am = 0; float mx = l0;
    if (l1 > mx) { mx = l1; am = 1; }
    if (l2 > mx) { mx = l2; am = 2; }
    float e0 = expf(l0 - mx), e1 = expf(l1 - mx), e2 = expf(l2 - mx);
    float inv = 1.f / (e0 + e1 + e2);
    float sc = (am == 0 ? e0 : (am == 1 ? e1 : e2)) * inv;
    wsel[b] = sc;
    int pos = atomicAdd(&cnt[am], 1);
    lists[am * kB + pos] = b;
    __threadfence();                       // publish lists/cnt (release)
    int tk = atomicAdd(ticket, 1);
    lastFlag = (tk == kB - 1) ? 1 : 0;
  }
  __syncthreads();
  if (lastFlag) {                          // last block: ALL threads pack tiles
    __threadfence();                       // acquire
    if (tid < 3) csh[tid] = cnt[tid];
    __syncthreads();
    int c0 = csh[0], c1 = csh[1], c2 = csh[2];
    int t0 = ((c0 + 7) & ~7) >> 2;         // tiles per expert (pairs -> even)
    int t1 = ((c1 + 7) & ~7) >> 2;
    int t2 = ((c2 + 7) & ~7) >> 2;
    int total = t0 + t1 + t2;
    if (tid == 0) *numTiles = total;
    for (int t = tid; t < kMaxTiles; t += 256) {
      int e = 0, base = 0, cc = 0;
      bool pad = false;
      if (t < t0) { e = 0; base = t; cc = c0; }
      else if (t < t0 + t1) { e = 1; base = t - t0; cc = c1; }
      else if (t < total) { e = 2; base = t - t0 - t1; cc = c2; }
      else pad = true;
      if (pad) {
        tileExpert[t] = 0;
        for (int s = 0; s < 4; ++s) tileBatch[t * 4 + s] = -1;
      } else {
        tileExpert[t] = e;
        for (int s = 0; s < 4; ++s) {
          int i = base * 4 + s;
          tileBatch[t * 4 + s] = (i < cc) ? lists[e * kB + i] : -1;
        }
      }
    }
  }
}

// ---------------- fused transpose + convert: both weight tensors ----------------
__global__ __launch_bounds__(256)
void k_transpose6(const void* __restrict__ w1src, const void* __restrict__ w2src,
                  __hip_bfloat16* __restrict__ w1dst, __hip_bfloat16* __restrict__ w2dst,
                  const int* __restrict__ flags) {
  int z = blockIdx.z;
  bool isW1 = (z < 3);
  int e = isW1 ? z : z - 3;
  bool f32 = (flags[isW1 ? 2 : 3] != 0);
  const float* sf = (const float*)(isW1 ? w1src : w2src);
  const unsigned short* sb = (const unsigned short*)(isW1 ? w1src : w2src);
  unsigned short* dst = (unsigned short*)(isW1 ? w1dst : w2dst);
  int K = isW1 ? kH : kF, N = isW1 ? kF : kH;
  int ntx = N / 64;
  int bx = blockIdx.x;
  int n0 = (bx % ntx) * 64, k0 = (bx / ntx) * 64;
  __shared__ __align__(16) unsigned short t[64][73];
  size_t eoff = (size_t)e * K * N;
  int tr = threadIdx.x >> 4;
  int tc4 = (threadIdx.x & 15) * 4;
#pragma unroll
  for (int i = 0; i < 4; ++i) {
    int r = tr + 16 * i;
    size_t idx = eoff + (size_t)(k0 + r) * N + n0 + tc4;
    if (f32) {
      float4 u = *(const float4*)(sf + idx);
      t[r][tc4] = f2bfb(u.x); t[r][tc4 + 1] = f2bfb(u.y);
      t[r][tc4 + 2] = f2bfb(u.z); t[r][tc4 + 3] = f2bfb(u.w);
    } else {
      ushort4 u = *(const ushort4*)(sb + idx);
      t[r][tc4] = u.x; t[r][tc4 + 1] = u.y; t[r][tc4 + 2] = u.z; t[r][tc4 + 3] = u.w;
    }
  }
  __syncthreads();
#pragma unroll
  for (int i = 0; i < 4; ++i) {
    int rn = tr + 16 * i;
    ushort4 v;
    v.x = t[tc4][rn]; v.y = t[tc4 + 1][rn]; v.z = t[tc4 + 2][rn]; v.w = t[tc4 + 3][rn];
    *(ushort4*)(dst + eoff + (size_t)(n0 + rn) * K + k0 + tc4) = v;
  }
}

// ---------------- per-batch convert x -> xconv (ffn1 A-staging order) ----------------
// xconv[b][t32(24)][mm(32)][qp(4)][8] ; content col = t32*32 + (qp^((mm>>1)&3))*8
__global__ __launch_bounds__(256)
void k_convert_x(const void* __restrict__ xv, const int* __restrict__ flags,
                 __hip_bfloat16* __restrict__ xconv) {
  __shared__ __align__(16) unsigned short xs[32][772];
  int b = blockIdx.x;
  bool fx = (flags[0] != 0);
  int tid = threadIdx.x;
  if (fx) {
    const float4* src = (const float4*)((const float*)xv + (size_t)b * kT * kH);
#pragma unroll
    for (int i = 0; i < 24; ++i) {
      int idx = i * 256 + tid;           // 0..6143
      float4 u = src[idx];
      int t = idx / 192, col = (idx - t * 192) * 4;
      ushort4 v;
      v.x = f2bfb(u.x); v.y = f2bfb(u.y); v.z = f2bfb(u.z); v.w = f2bfb(u.w);
      *(ushort4*)&xs[t][col] = v;
    }
  } else {
    const ushort4* src = (const ushort4*)((const unsigned short*)xv + (size_t)b * kT * kH);
#pragma unroll
    for (int i = 0; i < 24; ++i) {
      int idx = i * 256 + tid;
      ushort4 u = src[idx];
      int t = idx / 192, col = (idx - t * 192) * 4;
      *(ushort4*)&xs[t][col] = u;
    }
  }
  __syncthreads();
  unsigned short* dst = (unsigned short*)xconv + (size_t)b * 24576;
#pragma unroll
  for (int i = 0; i < 12; ++i) {
    int g = i * 256 + tid;               // 0..3071
    int t32 = g >> 7, r = g & 127, mm = r >> 2, qp = r & 3;
    int col = t32 * 32 + (qp ^ ((mm >> 1) & 3)) * 8;
    ushort4 lo = *(const ushort4*)&xs[mm][col];
    ushort4 hi = *(const ushort4*)&xs[mm][col + 4];
    short8 v;
    v[0] = lo.x; v[1] = lo.y; v[2] = lo.z; v[3] = lo.w;
    v[4] = hi.x; v[5] = hi.y; v[6] = hi.z; v[7] = hi.w;
    *(short8*)(dst + g * 8) = v;
  }
}

// ======== pipelined 256x256 GEMM skeleton (shared by ffn1/ffn2) ========
// 512 thr = 8 waves (wf 2 x wmv 4); swapped operands: mfma(Wfrag, Xfrag) -> C[n][m].
// LDS ring: 4 slots x 16384 shorts {X rows 0-255 | W rows 0-255}.
// Per iter t: stage(t+3); vmcnt(8); read frags(t); MFMA x32; s_barrier.

#define GEMM_CORE(NT, STAGE_CALL)                                              \
  STAGE_CALL(0); STAGE_CALL(1); STAGE_CALL(2);                                 \
  asm volatile("s_waitcnt vmcnt(8)" ::: "memory");                             \
  __builtin_amdgcn_s_barrier();                                                \
  for (int t = 0; t < (NT); ++t) {                                             \
    if (t + 3 < (NT)) {                                                        \
      STAGE_CALL(t + 3);                                                       \
      asm volatile("s_waitcnt vmcnt(8)" ::: "memory");                         \
    } else if (t + 3 == (NT)) {                                                \
      asm volatile("s_waitcnt vmcnt(4)" ::: "memory");                         \
    } else if (t + 2 == (NT)) {                                                \
      asm volatile("s_waitcnt vmcnt(0)" ::: "memory");                         \
    }                                                                          \
    int sl = (t & 3) * 16384;                                                  \
    short8 fw[8], fx8[4];                                                      \
    _Pragma("unroll")                                                          \
    for (int r = 0; r < 8; ++r)                                                \
      fw[r] = *(const short8*)&lds[sl + 8192 + (wf * 128 + r * 16 + lane16) * 32 + qx]; \
    _Pragma("unroll")                                                          \
    for (int c = 0; c < 4; ++c)                                                \
      fx8[c] = *(const short8*)&lds[sl + (wmv * 64 + c * 16 + lane16) * 32 + qx]; \
    __builtin_amdgcn_s_setprio(1);                                             \
    _Pragma("unroll")                                                          \
    for (int r = 0; r < 8; ++r)                                                \
      _Pragma("unroll")                                                        \
      for (int c = 0; c < 4; ++c)                                              \
        acc[r][c] = __builtin_amdgcn_mfma_f32_16x16x32_bf16(fw[r], fx8[c], acc[r][c], 0, 0, 0); \
    __builtin_amdgcn_s_setprio(0);                                             \
    __builtin_amdgcn_s_barrier();                                              \
  }

// ---------------- GEMM1: h = gelu(x @ W1[e] + b1) -> hbuf (ffn2 A-stream order) ----------------
__global__ __launch_bounds__(512, 2)
void k_ffn1(const __hip_bfloat16* __restrict__ xconv,
            const __hip_bfloat16* __restrict__ w1t,  // [E][F][H] bf16
            const __hip_bfloat16* __restrict__ b1,
            const int* __restrict__ tileExpert,
            const int* __restrict__ tileBatch,
            const int* __restrict__ numTiles,
            int tileOff, int chunk,
            __hip_bfloat16* __restrict__ hbuf) {
  extern __shared__ __align__(16) short lds[];
  int pairsC = chunk >> 1;
  int nblk = pairsC * 12;
  int lid = blockIdx.x * gridDim.y + blockIdx.y;
  if (lid >= nblk) return;
  int lpair = lid / 12;
  int nb = lid - lpair * 12;
  int nbase = nb * 256;                      // f-range of this block
  int tile0 = tileOff + 2 * lpair;
  if (tile0 >= *numTiles) return;
  int e = tileExpert[tile0];
  int tid = threadIdx.x;
  int m_l = tid >> 2;
  // staging batch indirection (per-lane, no local array)
  int bbS0 = tileBatch[tile0 * 4 + (m_l >> 5)];
  int bbS1 = tileBatch[tile0 * 4 + 4 + (m_l >> 5)];
  if (bbS0 < 0) bbS0 = 0;
  if (bbS1 < 0) bbS1 = 0;
  int g8 = ((tid & 3) ^ ((tid >> 3) & 3)) * 8;
  const __hip_bfloat16* w1e = w1t + (size_t)e * kF * kH;
  int aoff = ((m_l & 31) * 4 + (tid & 3)) * 8;
  const __hip_bfloat16* pA0 = xconv + (size_t)bbS0 * 24576 + aoff;
  const __hip_bfloat16* pA1 = xconv + (size_t)bbS1 * 24576 + aoff;
  const __hip_bfloat16* pB0 = w1e + (size_t)(nbase + m_l) * kH + g8;
  const __hip_bfloat16* pB1 = w1e + (size_t)(nbase + 128 + m_l) * kH + g8;
  int ldsT = tid * 8;
  int lane = tid & 63, wid = tid >> 6;
  int wf = wid >> 2, wmv = wid & 3;
  int lane16 = lane & 15, qf = lane >> 4;
  int qx = (qf ^ ((lane16 >> 1) & 3)) * 8;

  f32x4 acc[8][4];
#pragma unroll
  for (int r = 0; r < 8; ++r)
#pragma unroll
    for (int c = 0; c < 4; ++c) acc[r][c] = (f32x4)0.f;

#define STG1(kt) do { int s_ = ((kt) & 3) * 16384;                    \
    gld_lds16(pA0 + (kt) * 1024, &lds[s_ + ldsT]);                    \
    gld_lds16(pA1 + (kt) * 1024, &lds[s_ + 4096 + ldsT]);             \
    gld_lds16(pB0 + (kt) * 32, &lds[s_ + 8192 + ldsT]);               \
    gld_lds16(pB1 + (kt) * 32, &lds[s_ + 12288 + ldsT]); } while (0)

  GEMM_CORE(kNT1, STG1)
#undef STG1

  // ---- epilogue: gelu(acc+bias) -> LDS (bank-swizzled hbuf order) -> linear stores ----
  __syncthreads();
  int q4 = qf * 4;
#pragma unroll
  for (int r = 0; r < 8; ++r) {
    int flb = wf * 128 + r * 16 + q4;        // f-local base of 4-run (mult of 4)
    int t32l = flb >> 5;
    int fq = (flb >> 3) & 3;
    int j4 = flb & 7;                         // 0 or 4
    ushort4 bb4 = *(const ushort4*)((const unsigned short*)b1 + (size_t)e * kF + nbase + flb);
    float bi0 = bfu(bb4.x), bi1 = bfu(bb4.y), bi2 = bfu(bb4.z), bi3 = bfu(bb4.w);
#pragma unroll
    for (int c = 0; c < 4; ++c) {
      int m = wmv * 64 + c * 16 + lane16;
      int qp = fq ^ ((m >> 1) & 3);
      int w = t32l * 8192 + (m * 4 + qp) * 8 + j4;
      int phys = w ^ (((w >> 8) & 7) << 3);   // bank-spread, absorbed by copy-read
      ushort4 pk;
      pk.x = f2bfb(gelu_f(acc[r][c][0] + bi0));
      pk.y = f2bfb(gelu_f(acc[r][c][1] + bi1));
      pk.z = f2bfb(gelu_f(acc[r][c][2] + bi2));
      pk.w = f2bfb(gelu_f(acc[r][c][3] + bi3));
      *(ushort4*)&lds[phys] = pk;
    }
  }
  __syncthreads();
  unsigned short* hdst = (unsigned short*)hbuf + (size_t)lpair * kHbufPair + (size_t)(nbase >> 5) * 8192;
#pragma unroll
  for (int i = 0; i < 16; ++i) {
    int o = i * 4096 + ldsT;
    int phys = o ^ (((o >> 8) & 7) << 3);
    *(short8*)(hdst + o) = *(const short8*)&lds[phys];
  }
}

// ---------------- GEMM2: out = (h @ W2[e] + b2) * score ----------------
__global__ __launch_bounds__(512, 2)
void k_ffn2(const __hip_bfloat16* __restrict__ hbuf,
            const __hip_bfloat16* __restrict__ w2t,  // [E][H][F] bf16
            const __hip_bfloat16* __restrict__ b2,
            const float* __restrict__ wsel,
            const int* __restrict__ tileExpert,
            const int* __restrict__ tileBatch,
            const int* __restrict__ numTiles,
            int tileOff, int chunk,
            float* __restrict__ out) {
  extern __shared__ __align__(16) short lds[];
  int pairsC = chunk >> 1;
  int nblk = pairsC * 3;
  int lid = blockIdx.x * gridDim.y + blockIdx.y;
  if (lid >= nblk) return;
  int lpair = lid / 3;
  int nb = lid - lpair * 3;
  int nbase = nb * 256;                      // h-range of this block
  int tile0 = tileOff + 2 * lpair;
  if (tile0 >= *numTiles) return;
  int e = tileExpert[tile0];
  int tid = threadIdx.x;
  int m_l = tid >> 2;
  int g8 = ((tid & 3) ^ ((tid >> 3) & 3)) * 8;
  const __hip_bfloat16* w2e = w2t + (size_t)e * kF * kH;
  const __hip_bfloat16* pA = hbuf + (size_t)lpair * kHbufPair + tid * 8;
  const __hip_bfloat16* pB0 = w2e + (size_t)(nbase + m_l) * kF + g8;
  const __hip_bfloat16* pB1 = w2e + (size_t)(nbase + 128 + m_l) * kF + g8;
  int ldsT = tid * 8;
  int lane = tid & 63, wid = tid >> 6;
  int wf = wid >> 2, wmv = wid & 3;
  int lane16 = lane & 15, qf = lane >> 4;
  int qx = (qf ^ ((lane16 >> 1) & 3)) * 8;
  // per-wave batch slots (uniform)
  int slotBase = wmv * 2;
  int bbA = tileBatch[tile0 * 4 + slotBase];
  int bbB = tileBatch[tile0 * 4 + slotBase + 1];
  float scA = (bbA >= 0) ? wsel[bbA] : 0.f;
  float scB = (bbB >= 0) ? wsel[bbB] : 0.f;

  f32x4 acc[8][4];
#pragma unroll
  for (int r = 0; r < 8; ++r)
#pragma unroll
    for (int c = 0; c < 4; ++c) acc[r][c] = (f32x4)0.f;

#define STG2(kt) do { int s_ = ((kt) & 3) * 16384;                      \
    gld_lds16(pA + (size_t)(kt) * 8192, &lds[s_ + ldsT]);               \
    gld_lds16(pA + (size_t)(kt) * 8192 + 4096, &lds[s_ + 4096 + ldsT]); \
    gld_lds16(pB0 + (kt) * 32, &lds[s_ + 8192 + ldsT]);                 \
    gld_lds16(pB1 + (kt) * 32, &lds[s_ + 12288 + ldsT]); } while (0)

  GEMM_CORE(kNT2, STG2)
#undef STG2

  // ---- epilogue: contiguous float4 stores ----
  int q4 = qf * 4;
#pragma unroll
  for (int r = 0; r < 8; ++r) {
    int h0 = nbase + wf * 128 + r * 16 + q4;
    ushort4 bb4 = *(const ushort4*)((const unsigned short*)b2 + (size_t)e * kH + h0);
    float bi0 = bfu(bb4.x), bi1 = bfu(bb4.y), bi2 = bfu(bb4.z), bi3 = bfu(bb4.w);
#pragma unroll
    for (int c = 0; c < 4; ++c) {
      int bb = (c < 2) ? bbA : bbB;
      if (bb < 0) continue;
      float s = (c < 2) ? scA : scB;
      int m = wmv * 64 + c * 16 + lane16;
      float4 o;
      o.x = (acc[r][c][0] + bi0) * s;
      o.y = (acc[r][c][1] + bi1) * s;
      o.z = (acc[r][c][2] + bi2) * s;
      o.w = (acc[r][c][3] + bi3) * s;
      *(float4*)&out[(size_t)(bb * kT + (m & 31)) * kH + h0] = o;
    }
  }
}

}  // namespace

extern "C" void kernel_launch(void* const* d_in, const int* in_sizes, int n_in,
                              void* d_out, int out_size, void* d_ws, size_t ws_size,
                              hipStream_t stream) {
  (void)in_sizes; (void)n_in; (void)out_size;
  float* out = (float*)d_out;

  char* ws = (char*)d_ws;
  size_t off = 0;
  auto alloc = [&](size_t bytes) -> char* {
    char* p = ws + off;
    off = (off + bytes + 255) & ~(size_t)255;
    return p;
  };
  int*   flags      = (int*)alloc(16);      // x, Wg, W1, W2
  int*   cnt        = (int*)alloc(kE * 4);
  int*   ticket     = (int*)alloc(4);
  float* wsel       = (float*)alloc(kB * 4);
  int*   lists      = (int*)alloc((size_t)kE * kB * 4);
  int*   tileExpert = (int*)alloc(kMaxTiles * 4);
  int*   tileBatch  = (int*)alloc(kMaxTiles * 4 * 4);
  int*   numTiles   = (int*)alloc(4);
  __hip_bfloat16* w1t   = (__hip_bfloat16*)alloc((size_t)kE * kH * kF * 2);      // 14.2 MB
  __hip_bfloat16* w2t   = (__hip_bfloat16*)alloc((size_t)kE * kH * kF * 2);      // 14.2 MB
  __hip_bfloat16* xconv = (__hip_bfloat16*)alloc((size_t)kB * kT * kH * 2);      // 25.2 MB

  // adaptive hbuf chunk (deterministic in ws_size); EVEN (pair granularity)
  size_t pairBytes = (size_t)kHbufPair * 2;  // 1.5 MB per pair
  size_t tileBytes = pairBytes / 2;
  size_t avail = (ws_size > off + pairBytes) ? (ws_size - off) : pairBytes;
  int chunk = (int)(avail / tileBytes);
  if (chunk > kMaxChunk) chunk = kMaxChunk;
  chunk &= ~1;
  if (chunk < 2) chunk = 2;
  __hip_bfloat16* hbuf = (__hip_bfloat16*)alloc((size_t)(chunk / 2) * pairBytes);

  hipFuncSetAttribute((const void*)k_ffn1,
                      hipFuncAttributeMaxDynamicSharedMemorySize, 131072);
  hipFuncSetAttribute((const void*)k_ffn2,
                      hipFuncAttributeMaxDynamicSharedMemorySize, 131072);

  k_sniff_all<<<4, 256, 0, stream>>>((const unsigned short*)d_in[0],
                                     (const unsigned short*)d_in[1],
                                     (const unsigned short*)d_in[2],
                                     (const unsigned short*)d_in[4],
                                     flags, cnt, ticket);
  k_route<<<kB, 256, 0, stream>>>(d_in[0], d_in[1], flags, wsel, cnt, lists,
                                  ticket, tileExpert, tileBatch, numTiles);
  k_convert_x<<<kB, 256, 0, stream>>>(d_in[0], flags, xconv);
  k_transpose6<<<dim3(576, 1, 6), 256, 0, stream>>>(d_in[2], d_in[4], w1t, w2t, flags);
  for (int toff = 0; toff < kMaxTiles; toff += chunk) {
    int pairsC = chunk / 2;
    int nblk1 = pairsC * 12;
    int nblk2 = pairsC * 3;
    k_ffn1<<<dim3(8, (nblk1 + 7) / 8), 512, 131072, stream>>>(
        xconv, w1t, (const __hip_bfloat16*)d_in[3],
        tileExpert, tileBatch, numTiles, toff, chunk, hbuf);
    k_ffn2<<<dim3(8, (nblk2 + 7) / 8), 512, 131072, stream>>>(
        hbuf, w2t, (const __hip_bfloat16*)d_in[5], wsel,
        tileExpert, tileBatch, numTiles, toff, chunk, out);
  }
}

// Round 5
// 375.823 us; speedup vs baseline: 1.1429x; 1.0989x over previous
//
#include <hip/hip_runtime.h>
#include <hip/hip_bf16.h>
#include <cstdint>
#include <cstddef>

namespace {

constexpr int kB = 512, kT = 32, kH = 768, kF = 3072, kE = 3;
constexpr int kMaxTiles = 131;   // sum ceil(cnt_e/4) <= 131
constexpr int kMaxChunk = 131;
constexpr int kXPermTile = 128 * kH;   // 98304 elts per tile
constexpr int kHbufTile  = 128 * kF;   // 393216 elts per tile

typedef __attribute__((ext_vector_type(8))) short short8;
typedef __attribute__((ext_vector_type(4))) float f32x4;

__device__ __forceinline__ void gld_lds16(const void* g, void* l) {
  __builtin_amdgcn_global_load_lds(
      (const __attribute__((address_space(1))) void*)g,
      (__attribute__((address_space(3))) void*)l, 16, 0, 0);
}

__device__ __forceinline__ float bf2f(__hip_bfloat16 v) { return __bfloat162float(v); }
__device__ __forceinline__ float bfu(unsigned short u) {
  return __uint_as_float(((unsigned)u) << 16);
}
__device__ __forceinline__ unsigned short f2bfb(float f) {
  __hip_bfloat16 h = __float2bfloat16(f);
  return *reinterpret_cast<unsigned short*>(&h);
}

// exact-grade gelu: Abramowitz-Stegun 7.1.26 erf, |err| <= 1.5e-7
__device__ __forceinline__ float gelu_f(float v) {
  float av = fabsf(v);
  float z = av * 0.70710678118654752f;
  float t = __builtin_amdgcn_rcpf(fmaf(0.3275911f, z, 1.0f));
  float p = fmaf(fmaf(fmaf(fmaf(1.061405429f, t, -1.453152027f), t, 1.421413741f),
                      t, -0.284496736f), t, 0.254829592f) * t;
  float er = fmaf(-p, __expf(-z * z), 1.0f);   // erf(z), z >= 0
  return 0.5f * v + 0.5f * av * er;
}

// ---- fused per-tensor dtype sniff (4 blocks) + workspace re-init ----
__global__ void k_sniff_all(const unsigned short* __restrict__ x,
                            const unsigned short* __restrict__ g,
                            const unsigned short* __restrict__ w1,
                            const unsigned short* __restrict__ w2,
                            int* __restrict__ flags, int* __restrict__ cnt,
                            int* __restrict__ ticket) {
  int bb = blockIdx.x;
  if (bb == 0 && threadIdx.x < 4) {
    if (threadIdx.x < 3) cnt[threadIdx.x] = 0;
    else *ticket = 0;
  }
  const unsigned short* p = (bb == 0) ? x : (bb == 1) ? g : (bb == 2) ? w1 : w2;
  int nwords = (bb == 1) ? kE * kH : 4096;
  __shared__ int cnt_s;
  if (threadIdx.x == 0) cnt_s = 0;
  __syncthreads();
  int local = 0;
  for (int i = threadIdx.x; i < nwords; i += 256) {
    unsigned e = (p[i] >> 7) & 0xFF;
    if (e >= 0xC0) ++local;
  }
  atomicAdd(&cnt_s, local);
  __syncthreads();
  if (threadIdx.x == 0) flags[bb] = (cnt_s > 64) ? 1 : 0;
}

// ---------------- routing + PARALLEL tile packing in last block ----------------
__global__ void k_route(const void* __restrict__ xv, const void* __restrict__ Wgv,
                        const int* __restrict__ flags,
                        float* __restrict__ wsel,
                        int* __restrict__ cnt, int* __restrict__ lists,
                        int* __restrict__ ticket,
                        int* __restrict__ tileExpert, int* __restrict__ tileBatch,
                        int* __restrict__ numTiles) {
  bool fx = (flags[0] != 0), fg = (flags[1] != 0);
  int b = blockIdx.x;
  int tid = threadIdx.x;
  float a0 = 0.f, a1 = 0.f, a2 = 0.f;
  if (tid < 192) {   // 192 * float4 = 768 h
    float m0 = 0.f, m1 = 0.f, m2 = 0.f, m3 = 0.f;
    if (fx) {
      const float4* xr = (const float4*)((const float*)xv + (size_t)b * kT * kH) + tid;
#pragma unroll 8
      for (int t = 0; t < kT; ++t) {
        float4 u = xr[t * 192];
        m0 += u.x; m1 += u.y; m2 += u.z; m3 += u.w;
      }
    } else {
      const ushort4* xr = (const ushort4*)((const unsigned short*)xv + (size_t)b * kT * kH) + tid;
#pragma unroll 8
      for (int t = 0; t < kT; ++t) {
        ushort4 u = xr[t * 192];
        m0 += bfu(u.x); m1 += bfu(u.y); m2 += bfu(u.z); m3 += bfu(u.w);
      }
    }
    const float inv = 1.f / kT;
    m0 *= inv; m1 *= inv; m2 *= inv; m3 *= inv;
#pragma unroll
    for (int e = 0; e < kE; ++e) {
      float w0, w1v, w2v, w3;
      int base = e * kH + tid * 4;
      if (fg) {
        float4 u = *(const float4*)((const float*)Wgv + base);
        w0 = u.x; w1v = u.y; w2v = u.z; w3 = u.w;
      } else {
        ushort4 u = *(const ushort4*)((const unsigned short*)Wgv + base);
        w0 = bfu(u.x); w1v = bfu(u.y); w2v = bfu(u.z); w3 = bfu(u.w);
      }
      float d = m0 * w0 + m1 * w1v + m2 * w2v + m3 * w3;
      if (e == 0) a0 = d; else if (e == 1) a1 = d; else a2 = d;
    }
  }
  __shared__ float red[3][256];
  __shared__ int lastFlag;
  __shared__ int csh[3];
  red[0][tid] = a0; red[1][tid] = a1; red[2][tid] = a2;
  __syncthreads();
  for (int s2 = 128; s2 > 0; s2 >>= 1) {
    if (tid < s2) {
      red[0][tid] += red[0][tid + s2];
      red[1][tid] += red[1][tid + s2];
      red[2][tid] += red[2][tid + s2];
    }
    __syncthreads();
  }
  if (tid == 0) {
    float l0 = red[0][0], l1 = red[1][0], l2 = red[2][0];
    int am = 0; float mx = l0;
    if (l1 > mx) { mx = l1; am = 1; }
    if (l2 > mx) { mx = l2; am = 2; }
    float e0 = expf(l0 - mx), e1 = expf(l1 - mx), e2 = expf(l2 - mx);
    float inv = 1.f / (e0 + e1 + e2);
    float sc = (am == 0 ? e0 : (am == 1 ? e1 : e2)) * inv;
    wsel[b] = sc;
    int pos = atomicAdd(&cnt[am], 1);
    lists[am * kB + pos] = b;
    __threadfence();                       // publish lists/cnt (release)
    int tk = atomicAdd(ticket, 1);
    lastFlag = (tk == kB - 1) ? 1 : 0;
  }
  __syncthreads();
  if (lastFlag) {                          // last block: ALL threads pack tiles
    __threadfence();                       // acquire
    if (tid < 3) csh[tid] = cnt[tid];
    __syncthreads();
    int c0 = csh[0], c1 = csh[1], c2 = csh[2];
    int t0 = ((c0 + 3) & ~3) >> 2;         // ceil(c/4) tiles per expert
    int t1 = ((c1 + 3) & ~3) >> 2;
    int t2 = ((c2 + 3) & ~3) >> 2;
    int total = t0 + t1 + t2;
    if (tid == 0) *numTiles = total;
    for (int t = tid; t < kMaxTiles; t += 256) {
      int e = 0, base = 0, cc = 0;
      bool pad = false;
      if (t < t0) { e = 0; base = t; cc = c0; }
      else if (t < t0 + t1) { e = 1; base = t - t0; cc = c1; }
      else if (t < total) { e = 2; base = t - t0 - t1; cc = c2; }
      else pad = true;
      if (pad) {
        tileExpert[t] = 0;
        for (int s = 0; s < 4; ++s) tileBatch[t * 4 + s] = -1;
      } else {
        tileExpert[t] = e;
        for (int s = 0; s < 4; ++s) {
          int i = base * 4 + s;
          tileBatch[t * 4 + s] = (i < cc) ? lists[e * kB + i] : -1;
        }
      }
    }
  }
}

// ---------------- fused transpose + convert: both weight tensors, one launch ----------------
// z<3: W1 [e][H][F] -> w1t [e][F][H]; z>=3: W2 [e][F][H] -> w2t [e][H][F]
__global__ __launch_bounds__(256)
void k_transpose6(const void* __restrict__ w1src, const void* __restrict__ w2src,
                  __hip_bfloat16* __restrict__ w1dst, __hip_bfloat16* __restrict__ w2dst,
                  const int* __restrict__ flags) {
  int z = blockIdx.z;
  bool isW1 = (z < 3);
  int e = isW1 ? z : z - 3;
  bool f32 = (flags[isW1 ? 2 : 3] != 0);
  const float* sf = (const float*)(isW1 ? w1src : w2src);
  const unsigned short* sb = (const unsigned short*)(isW1 ? w1src : w2src);
  unsigned short* dst = (unsigned short*)(isW1 ? w1dst : w2dst);
  int K = isW1 ? kH : kF, N = isW1 ? kF : kH;
  int ntx = N / 64;
  int bx = blockIdx.x;
  int n0 = (bx % ntx) * 64, k0 = (bx / ntx) * 64;
  __shared__ __align__(16) unsigned short t[64][73];
  size_t eoff = (size_t)e * K * N;
  int tr = threadIdx.x >> 4;
  int tc4 = (threadIdx.x & 15) * 4;
#pragma unroll
  for (int i = 0; i < 4; ++i) {
    int r = tr + 16 * i;
    size_t idx = eoff + (size_t)(k0 + r) * N + n0 + tc4;
    if (f32) {
      float4 u = *(const float4*)(sf + idx);
      t[r][tc4] = f2bfb(u.x); t[r][tc4 + 1] = f2bfb(u.y);
      t[r][tc4 + 2] = f2bfb(u.z); t[r][tc4 + 3] = f2bfb(u.w);
    } else {
      ushort4 u = *(const ushort4*)(sb + idx);
      t[r][tc4] = u.x; t[r][tc4 + 1] = u.y; t[r][tc4 + 2] = u.z; t[r][tc4 + 3] = u.w;
    }
  }
  __syncthreads();
#pragma unroll
  for (int i = 0; i < 4; ++i) {
    int rn = tr + 16 * i;
    ushort4 v;
    v.x = t[tc4][rn]; v.y = t[tc4 + 1][rn]; v.z = t[tc4 + 2][rn]; v.w = t[tc4 + 3][rn];
    *(ushort4*)(dst + eoff + (size_t)(n0 + rn) * K + k0 + tc4) = v;
  }
}

// ---------------- convert + permute x into ffn1 A-staging order (tile-gathered) ----------------
// xperm[tile][kblk(12)][slot(1024)*8], slot = kk*512 + m*4 + (q ^ ((m>>1)&3))
__global__ __launch_bounds__(256)
void k_convert_x(const void* __restrict__ xv, const int* __restrict__ flags,
                 const int* __restrict__ tileBatch, const int* __restrict__ numTiles,
                 __hip_bfloat16* __restrict__ xperm) {
  int tile = blockIdx.y;
  if (tile >= *numTiles) return;
  int kblk = blockIdx.x;
  bool fx = (flags[0] != 0);
  const float* xf = (const float*)xv;
  const __hip_bfloat16* xb = (const __hip_bfloat16*)xv;
  int tb0 = tileBatch[tile * 4];
  if (tb0 < 0) tb0 = 0;
  int tb[4];
#pragma unroll
  for (int s = 0; s < 4; ++s) {
    int bb = tileBatch[tile * 4 + s];
    tb[s] = (bb < 0) ? tb0 : bb;
  }
  int tid = threadIdx.x;
  short8* dst = (short8*)(xperm + (size_t)tile * kXPermTile + kblk * 8192);
#pragma unroll
  for (int i = 0; i < 4; ++i) {
    int s = i * 256 + tid;
    int m = (s >> 2) & 127, kk = s >> 9;
    int q = (s & 3) ^ ((s >> 3) & 3);   // (m>>1)&3 == (s>>3)&3
    int row = tb[m >> 5] * kT + (m & 31);
    size_t src = (size_t)row * kH + kblk * 64 + kk * 32 + q * 8;
    short8 v;
    if (fx) {
      float4 u = *(const float4*)(xf + src);
      float4 w = *(const float4*)(xf + src + 4);
      v[0] = f2bfb(u.x); v[1] = f2bfb(u.y); v[2] = f2bfb(u.z); v[3] = f2bfb(u.w);
      v[4] = f2bfb(w.x); v[5] = f2bfb(w.y); v[6] = f2bfb(w.z); v[7] = f2bfb(w.w);
    } else {
      v = *(const short8*)(xb + src);
    }
    dst[s] = v;
  }
}

// ---------------- GEMM1: h = gelu(x @ W1[e] + b1), hbuf in ffn2-A-staging order ----------------
__global__ __launch_bounds__(256, 2)
void k_ffn1(const __hip_bfloat16* __restrict__ xperm,
            const __hip_bfloat16* __restrict__ w1t,  // [E][F][H] bf16
            const __hip_bfloat16* __restrict__ b1,
            const int* __restrict__ tileExpert,
            const int* __restrict__ numTiles,
            int tileOff,
            __hip_bfloat16* __restrict__ hbuf) {
  int j = blockIdx.y;
  int local = j / 3;
  int tile = local + tileOff;
  if (tile >= *numTiles) return;
  int nIdx = 8 * (j % 3) + blockIdx.x;
  int nbase = nIdx * 128;
  int e = tileExpert[tile];
  __shared__ __align__(16) short ldsbuf[16384];   // A: [0,8192) B: [8192,16384)
  short* ldsA = ldsbuf;
  short* ldsB = ldsbuf + 8192;
  int tid = threadIdx.x;
  int lane = tid & 63, wid = tid >> 6;
  int wm = wid >> 1, wn = wid & 1;
  int lane16 = lane & 15, qf = lane >> 4;
  int swzl = (lane16 >> 1) & 3;
  int qx = (qf ^ swzl) * 8;

  f32x4 acc[4][4];
#pragma unroll
  for (int r = 0; r < 4; ++r)
#pragma unroll
    for (int c = 0; c < 4; ++c) acc[r][c] = (f32x4)0.f;

  const __hip_bfloat16* w1e = w1t + (size_t)e * kF * kH;
  const __hip_bfloat16* xtile = xperm + (size_t)tile * kXPermTile;
  const __hip_bfloat16* gB[4];
  short* lA[4];
  short* lB[4];
  int aoff[4];
#pragma unroll
  for (int it = 0; it < 4; ++it) {
    int s = it * 256 + tid;
    int m = (s >> 2) & 127, kk = s >> 9;
    int q = (s & 3) ^ ((s >> 3) & 3);
    aoff[it] = s * 8;
    gB[it] = w1e + (size_t)(nbase + m) * kH + kk * 32 + q * 8;
    lA[it] = &ldsA[s * 8];
    lB[it] = &ldsB[s * 8];
  }

  for (int k0 = 0; k0 < kH; k0 += 64) {
#pragma unroll
    for (int it = 0; it < 4; ++it) gld_lds16(xtile + k0 * 128 + aoff[it], lA[it]);
#pragma unroll
    for (int it = 0; it < 4; ++it) gld_lds16(gB[it] + k0, lB[it]);
    __syncthreads();
#pragma unroll
    for (int kk = 0; kk < 2; ++kk) {
      short8 af[4], bfr[4];
#pragma unroll
      for (int r = 0; r < 4; ++r) {
        int mr = wm * 64 + r * 16 + lane16;
        af[r] = *(const short8*)&ldsA[(kk * 512 + mr * 4) * 8 + qx];
      }
#pragma unroll
      for (int c = 0; c < 4; ++c) {
        int mb = wn * 64 + c * 16 + lane16;
        bfr[c] = *(const short8*)&ldsB[(kk * 512 + mb * 4) * 8 + qx];
      }
#pragma unroll
      for (int r = 0; r < 4; ++r)
#pragma unroll
        for (int c = 0; c < 4; ++c)
          acc[r][c] = __builtin_amdgcn_mfma_f32_16x16x32_bf16(af[r], bfr[c], acc[r][c], 0, 0, 0);
    }
    __syncthreads();
  }

  // epilogue: gelu(acc+bias) -> LDS in hbuf-staged order -> contiguous 16B global stores
  __hip_bfloat16* htile = hbuf + (size_t)local * kHbufTile;
  unsigned short* uls = (unsigned short*)ldsbuf;
  int q4 = qf * 4;
#pragma unroll
  for (int c = 0; c < 4; ++c) {
    int nn = wn * 64 + c * 16 + lane16;           // n - nbase in [0,128)
    float bias = bf2f(b1[e * kF + nbase + nn]);
    int lbase = (nn >> 6) * 8192 + ((nn >> 5) & 1) * 4096 + (nn & 7);
    int qn = (nn >> 3) & 3;
#pragma unroll
    for (int r = 0; r < 4; ++r) {
#pragma unroll
      for (int g = 0; g < 4; ++g) {
        int m = wm * 64 + r * 16 + q4 + g;
        float v = acc[r][c][g] + bias;
        uls[lbase + (m * 4 + (qn ^ ((m >> 1) & 3))) * 8] = f2bfb(gelu_f(v));
      }
    }
  }
  __syncthreads();
  unsigned short* dstg = (unsigned short*)htile + (size_t)(nbase >> 6) * 8192;
#pragma unroll
  for (int i = 0; i < 8; ++i) {
    int s = i * 2048 + tid * 8;
    *(short8*)(dstg + s) = *(const short8*)(uls + s);
  }
}

// ---------------- GEMM2: out = (h @ W2[e] + b2) * score, f32 scatter ----------------
__global__ __launch_bounds__(256, 2)
void k_ffn2(const __hip_bfloat16* __restrict__ hbuf,
            const __hip_bfloat16* __restrict__ w2t,  // [E][H][F] bf16
            const __hip_bfloat16* __restrict__ b2,
            const float* __restrict__ wsel,
            const int* __restrict__ tileExpert,
            const int* __restrict__ tileBatch,
            const int* __restrict__ numTiles,
            int tileOff, int chunk,
            float* __restrict__ out) {
  int j = blockIdx.y;
  int local = blockIdx.x + 8 * (j / 6);
  if (local >= chunk) return;
  int tile = local + tileOff;
  if (tile >= *numTiles) return;
  int nbase = (j % 6) * 128;
  int e = tileExpert[tile];
  int tbraw[4];
  float sc[4];
#pragma unroll
  for (int s = 0; s < 4; ++s) {
    int bb = tileBatch[tile * 4 + s];
    tbraw[s] = bb;
    sc[s] = (bb >= 0) ? wsel[bb] : 0.f;
  }
  __shared__ __align__(16) short ldsA[8192];
  __shared__ __align__(16) short ldsB[8192];
  int tid = threadIdx.x;
  int lane = tid & 63, wid = tid >> 6;
  int wm = wid >> 1, wn = wid & 1;
  int lane16 = lane & 15, qf = lane >> 4;
  int swzl = (lane16 >> 1) & 3;
  int qx = (qf ^ swzl) * 8;

  f32x4 acc[4][4];
#pragma unroll
  for (int r = 0; r < 4; ++r)
#pragma unroll
    for (int c = 0; c < 4; ++c) acc[r][c] = (f32x4)0.f;

  const __hip_bfloat16* w2e = w2t + (size_t)e * kF * kH;
  const __hip_bfloat16* htile = hbuf + (size_t)local * kHbufTile;
  const __hip_bfloat16* gB[4];
  short* lA[4];
  short* lB[4];
  int aoff[4];
#pragma unroll
  for (int it = 0; it < 4; ++it) {
    int s = it * 256 + tid;
    int m = (s >> 2) & 127, kk = s >> 9;
    int q = (s & 3) ^ ((s >> 3) & 3);
    aoff[it] = s * 8;
    gB[it] = w2e + (size_t)(nbase + m) * kF + kk * 32 + q * 8;
    lA[it] = &ldsA[s * 8];
    lB[it] = &ldsB[s * 8];
  }

  for (int k0 = 0; k0 < kF; k0 += 64) {
#pragma unroll
    for (int it = 0; it < 4; ++it) gld_lds16(htile + k0 * 128 + aoff[it], lA[it]);
#pragma unroll
    for (int it = 0; it < 4; ++it) gld_lds16(gB[it] + k0, lB[it]);
    __syncthreads();
#pragma unroll
    for (int kk = 0; kk < 2; ++kk) {
      short8 af[4], bfr[4];
#pragma unroll
      for (int r = 0; r < 4; ++r) {
        int mr = wm * 64 + r * 16 + lane16;
        af[r] = *(const short8*)&ldsA[(kk * 512 + mr * 4) * 8 + qx];
      }
#pragma unroll
      for (int c = 0; c < 4; ++c) {
        int mb = wn * 64 + c * 16 + lane16;
        bfr[c] = *(const short8*)&ldsB[(kk * 512 + mb * 4) * 8 + qx];
      }
#pragma unroll
      for (int r = 0; r < 4; ++r)
#pragma unroll
        for (int c = 0; c < 4; ++c)
          acc[r][c] = __builtin_amdgcn_mfma_f32_16x16x32_bf16(af[r], bfr[c], acc[r][c], 0, 0, 0);
    }
    __syncthreads();
  }

  int q4 = qf * 4;
#pragma unroll
  for (int c = 0; c < 4; ++c) {
    int ncol = wn * 64 + c * 16 + lane16;
    float bias = bf2f(b2[e * kH + nbase + ncol]);
#pragma unroll
    for (int r = 0; r < 4; ++r) {
      int s = (wm * 64 + r * 16) >> 5;
      int bb = tbraw[s];
      if (bb < 0) continue;
      float scale = sc[s];
#pragma unroll
      for (int g = 0; g < 4; ++g) {
        int m = wm * 64 + r * 16 + q4 + g;
        float v = (acc[r][c][g] + bias) * scale;
        out[((size_t)(bb * kT + (m & 31))) * kH + nbase + ncol] = v;
      }
    }
  }
}

}  // namespace

extern "C" void kernel_launch(void* const* d_in, const int* in_sizes, int n_in,
                              void* d_out, int out_size, void* d_ws, size_t ws_size,
                              hipStream_t stream) {
  (void)in_sizes; (void)n_in; (void)out_size;
  float* out = (float*)d_out;

  char* ws = (char*)d_ws;
  size_t off = 0;
  auto alloc = [&](size_t bytes) -> char* {
    char* p = ws + off;
    off = (off + bytes + 255) & ~(size_t)255;
    return p;
  };
  int*   flags      = (int*)alloc(16);      // x, Wg, W1, W2
  int*   cnt        = (int*)alloc(kE * 4);
  int*   ticket     = (int*)alloc(4);
  float* wsel       = (float*)alloc(kB * 4);
  int*   lists      = (int*)alloc((size_t)kE * kB * 4);
  int*   tileExpert = (int*)alloc(kMaxTiles * 4);
  int*   tileBatch  = (int*)alloc(kMaxTiles * 4 * 4);
  int*   numTiles   = (int*)alloc(4);
  __hip_bfloat16* w1t   = (__hip_bfloat16*)alloc((size_t)kE * kH * kF * 2);      // 14.2 MB
  __hip_bfloat16* w2t   = (__hip_bfloat16*)alloc((size_t)kE * kH * kF * 2);      // 14.2 MB
  __hip_bfloat16* xperm = (__hip_bfloat16*)alloc((size_t)kMaxTiles * kXPermTile * 2);  // 25.8 MB

  // adaptive hbuf chunk (deterministic in ws_size)
  size_t tileBytes = (size_t)kHbufTile * 2;  // 786432
  size_t avail = (ws_size > off + tileBytes) ? (ws_size - off) : tileBytes;
  int chunk = (int)(avail / tileBytes);
  if (chunk > kMaxChunk) chunk = kMaxChunk;
  if (chunk < 1) chunk = 1;
  __hip_bfloat16* hbuf = (__hip_bfloat16*)alloc((size_t)chunk * tileBytes);

  k_sniff_all<<<4, 256, 0, stream>>>((const unsigned short*)d_in[0],
                                     (const unsigned short*)d_in[1],
                                     (const unsigned short*)d_in[2],
                                     (const unsigned short*)d_in[4],
                                     flags, cnt, ticket);
  k_route<<<kB, 256, 0, stream>>>(d_in[0], d_in[1], flags, wsel, cnt, lists,
                                  ticket, tileExpert, tileBatch, numTiles);
  k_convert_x<<<dim3(kH / 64, kMaxTiles), 256, 0, stream>>>(d_in[0], flags, tileBatch,
                                                            numTiles, xperm);
  k_transpose6<<<dim3(576, 1, 6), 256, 0, stream>>>(d_in[2], d_in[4], w1t, w2t, flags);
  for (int toff = 0; toff < kMaxTiles; toff += chunk) {
    k_ffn1<<<dim3(8, 3 * chunk), 256, 0, stream>>>(xperm, w1t,
                                                   (const __hip_bfloat16*)d_in[3],
                                                   tileExpert, numTiles, toff, hbuf);
    int rows2 = (chunk + 7) / 8;
    k_ffn2<<<dim3(8, 6 * rows2), 256, 0, stream>>>(hbuf, w2t,
                                                   (const __hip_bfloat16*)d_in[5], wsel,
                                                   tileExpert, tileBatch, numTiles,
                                                   toff, chunk, out);
  }
}